// Round 13
// baseline (197.367 us; speedup 1.0000x reference)
//
#include <hip/hip_runtime.h>
#include <cstddef>

// B=4, L=4096 (=64x64), d_model=512, d_inner=512, dt_rank=32, d_state=1
// GEMMs on MFMA, uniform 2-term bf16 split: C = bf16(A)*(Whi + Wlo).
// kt-outer 3-panel staging (48 KB LDS), XCD-chunked swizzle.
// bf16 intermediates (all pre-LN, LN-suppressed): xin, z, xs, ypre/y_t.
// scan_sfconv: thread-serial(16)+wave-scan; xs kept in regs; bf16 ypre out.

typedef __attribute__((ext_vector_type(8))) short short8;
typedef __attribute__((ext_vector_type(8))) unsigned short ushort8_t;
typedef __attribute__((ext_vector_type(4))) float f32x4;

__device__ __forceinline__ void gload16(const void* g, void* l) {
  __builtin_amdgcn_global_load_lds(
      (const __attribute__((address_space(1))) void*)g,
      (__attribute__((address_space(3))) void*)l, 16, 0, 0);
}

__device__ __forceinline__ void bf16split(float v, unsigned short& h, unsigned short& l) {
  unsigned u = __float_as_uint(v);
  unsigned uh = (u + 0x7fffu + ((u >> 16) & 1u)) & 0xffff0000u;
  h = (unsigned short)(uh >> 16);
  float rem = v - __uint_as_float(uh);
  unsigned ur = __float_as_uint(rem);
  l = (unsigned short)((ur + 0x7fffu + ((ur >> 16) & 1u)) >> 16);
}

__device__ __forceinline__ unsigned short bf16rne(float v) {
  unsigned u = __float_as_uint(v);
  return (unsigned short)((u + 0x7fffu + ((u >> 16) & 1u)) >> 16);
}

__device__ __forceinline__ float b2f(unsigned short u) {
  return __uint_as_float((unsigned)u << 16);
}

// ---------------- fp32 -> bf16 hi/lo split (weights) ------------------------
__global__ __launch_bounds__(256)
void split_k(const float* __restrict__ in, unsigned short* __restrict__ hi,
             unsigned short* __restrict__ lo, int n4)
{
  int i = blockIdx.x * 256 + threadIdx.x;
  if (i >= n4) return;
  float4 v = ((const float4*)in)[i];
  float vv[4] = {v.x, v.y, v.z, v.w};
  unsigned short h[4], l[4];
#pragma unroll
  for (int j = 0; j < 4; ++j) bf16split(vv[j], h[j], l[j]);
  ((ushort4*)hi)[i] = make_ushort4(h[0], h[1], h[2], h[3]);
  ((ushort4*)lo)[i] = make_ushort4(l[0], l[1], l[2], l[3]);
}

// ---------------- fp32 -> bf16 RNE (activations, hi only) -------------------
__global__ __launch_bounds__(256)
void cvt_hi_k(const float* __restrict__ in, unsigned short* __restrict__ hi, int n4)
{
  int i = blockIdx.x * 256 + threadIdx.x;
  if (i >= n4) return;
  float4 v = ((const float4*)in)[i];
  ((ushort4*)hi)[i] = make_ushort4(bf16rne(v.x), bf16rne(v.y), bf16rne(v.z), bf16rne(v.w));
}

// ---------------- 2-term bf16 MFMA GEMM: C = A*(Whi+Wlo)^T ------------------
// 128x128 tile, 4 waves (2x2 of 64x64), 16x16x32 MFMA, BK=64, K=512.
// MODE0: xin (ch-major bf16) + z (px-major bf16). MODE1: px-major fp32 out.
template<int MODE>
__global__ __launch_bounds__(256)
void gemm_mfma(const unsigned short* __restrict__ Ag_, const unsigned short* __restrict__ Whi,
               const unsigned short* __restrict__ Wlo,
               void* __restrict__ o1v, void* __restrict__ o2v)
{
  __shared__ char smem[49152];
  unsigned short* sA  = (unsigned short*)smem;
  unsigned short* sBh = (unsigned short*)(smem + 16384);
  unsigned short* sBl = (unsigned short*)(smem + 32768);
  const int tid = threadIdx.x;
  const int wave = tid >> 6, lane = tid & 63;

  const int nwg = gridDim.x;
  const int q = nwg >> 3, r = nwg & 7;
  const int xcd = blockIdx.x & 7, wi = blockIdx.x >> 3;
  const int logical = (xcd < r ? xcd * (q + 1) : r * (q + 1) + (xcd - r) * q) + wi;
  const int NTN = (MODE == 0) ? 8 : 4;
  const int tm = logical / NTN, tn = logical - tm * NTN;
  const int m0 = tm << 7, n0 = tn << 7;

  const int wm = (wave & 1) << 6;
  const int wn = (wave >> 1) << 6;
  const int q16 = (lane >> 4) << 4;
  const int l15 = lane & 15;

  int srow[4], scol[4];
#pragma unroll
  for (int c = 0; c < 4; ++c) {
    int o = (wave << 12) + (c << 10) + (lane << 4);
    int row = o >> 7;
    srow[c] = row;
    scol[c] = (o & 127) ^ ((row & 7) << 4);
  }

  f32x4 acc[4][4];
#pragma unroll
  for (int i = 0; i < 4; ++i)
#pragma unroll
    for (int j = 0; j < 4; ++j) acc[i][j] = (f32x4){0.f, 0.f, 0.f, 0.f};

  for (int kt = 0; kt < 8; ++kt) {
    int kb = kt << 7;
    __syncthreads();
#pragma unroll
    for (int c = 0; c < 4; ++c) {
      size_t ga = (size_t)(m0 + srow[c]) * 1024 + kb + scol[c];
      size_t gb = (size_t)(n0 + srow[c]) * 1024 + kb + scol[c];
      int lo_ = (wave << 12) + (c << 10);
      gload16((const char*)Ag_ + ga, (char*)sA + lo_);
      gload16((const char*)Whi + gb, (char*)sBh + lo_);
      gload16((const char*)Wlo + gb, (char*)sBl + lo_);
    }
    __syncthreads();
#pragma unroll
    for (int ks = 0; ks < 2; ++ks) {
      short8 af[4], bh[4], bl[4];
#pragma unroll
      for (int i = 0; i < 4; ++i) {
        int row = wm + (i << 4) + l15;
        int cb = ((ks << 6) + q16) ^ ((row & 7) << 4);
        af[i] = *(const short8*)((const char*)sA + (row << 7) + cb);
      }
#pragma unroll
      for (int j = 0; j < 4; ++j) {
        int row = wn + (j << 4) + l15;
        int cb = ((ks << 6) + q16) ^ ((row & 7) << 4);
        bh[j] = *(const short8*)((const char*)sBh + (row << 7) + cb);
        bl[j] = *(const short8*)((const char*)sBl + (row << 7) + cb);
      }
#pragma unroll
      for (int i = 0; i < 4; ++i)
#pragma unroll
        for (int j = 0; j < 4; ++j) {
          acc[i][j] = __builtin_amdgcn_mfma_f32_16x16x32_bf16(af[i], bh[j], acc[i][j], 0, 0, 0);
          acc[i][j] = __builtin_amdgcn_mfma_f32_16x16x32_bf16(af[i], bl[j], acc[i][j], 0, 0, 0);
        }
    }
  }

  if (MODE == 0) {
    unsigned short* xinb = (unsigned short*)o1v;
    unsigned short* zb16 = (unsigned short*)o2v;
    const int mb_base = m0 + wm + ((lane >> 4) << 2);
#pragma unroll
    for (int j = 0; j < 4; ++j) {
      int n = n0 + wn + (j << 4) + l15;
#pragma unroll
      for (int i = 0; i < 4; ++i) {
        int mb = mb_base + (i << 4);
        if (n < 512) {
          int b = mb >> 12, l = mb & 4095;
          ushort4 hv = make_ushort4(bf16rne(acc[i][j][0]), bf16rne(acc[i][j][1]),
                                    bf16rne(acc[i][j][2]), bf16rne(acc[i][j][3]));
          *(ushort4*)&xinb[((size_t)(b * 512 + n) << 12) + l] = hv;
        } else {
#pragma unroll
          for (int rr = 0; rr < 4; ++rr)
            zb16[(size_t)(mb + rr) * 512 + (n - 512)] = bf16rne(acc[i][j][rr]);
        }
      }
    }
  } else {
    float* o1 = (float*)o1v;
    // stage C tile through LDS in two 64x128 halves; store coalesced float4
    float* sC = (float*)smem;           // 64 x 128 fp32 = 32 KB (fits 48 KB)
    const int i_base = (lane >> 4) << 2;
#pragma unroll
    for (int half = 0; half < 2; ++half) {
      __syncthreads();
      if ((wave & 1) == half) {
#pragma unroll
        for (int j = 0; j < 4; ++j) {
          int nl = wn + (j << 4) + l15;
#pragma unroll
          for (int i = 0; i < 4; ++i) {
            int mloc = (i << 4) + i_base;
#pragma unroll
            for (int rr = 0; rr < 4; ++rr)
              sC[(mloc + rr) * 128 + nl] = acc[i][j][rr];
          }
        }
      }
      __syncthreads();
      int cx = (tid & 31) << 2;
      int r0 = tid >> 5;
#pragma unroll
      for (int it = 0; it < 8; ++it) {
        int row = r0 + (it << 3);
        *(float4*)&o1[(size_t)(m0 + (half << 6) + row) * 512 + n0 + cx] =
            *(float4*)&sC[row * 128 + cx];
      }
    }
  }
}

// -------- depthwise 3x3 SAME (zero pad) + bias + silu, bf16 in/out ----------
__global__ __launch_bounds__(256)
void conv_silu_k(const unsigned short* __restrict__ xin, const float* __restrict__ w,
                 const float* __restrict__ bias, unsigned short* __restrict__ xs)
{
  __shared__ float t[64][65];
  int plane = blockIdx.x;          // b*512 + d
  int d = plane & 511;
  int tid = threadIdx.x;
  const unsigned short* src = xin + (size_t)plane * 4096;
  int l0 = tid << 4, row = tid >> 2, c0 = (tid & 3) << 4;
  ushort8_t v0 = *(const ushort8_t*)&src[l0];
  ushort8_t v1 = *(const ushort8_t*)&src[l0 + 8];
#pragma unroll
  for (int j = 0; j < 8; ++j) {
    t[row][c0 + j]     = b2f(v0[j]);
    t[row][c0 + 8 + j] = b2f(v1[j]);
  }
  float wv[9];
#pragma unroll
  for (int j = 0; j < 9; j++) wv[j] = w[d * 9 + j];
  float bv = bias[d];
  __syncthreads();
  unsigned short* dst = xs + (size_t)plane * 4096;
#pragma unroll
  for (int i = 0; i < 16; i++) {
    int idx = tid + i * 256;
    int y = idx >> 6, x = idx & 63;
    float s = bv;
#pragma unroll
    for (int u = 0; u < 3; u++)
#pragma unroll
      for (int v = 0; v < 3; v++) {
        int yy = y + u - 1, xx = x + v - 1;
        if (yy >= 0 && yy < 64 && xx >= 0 && xx < 64)
          s = fmaf(wv[u * 3 + v], t[yy][xx], s);
      }
    dst[idx] = bf16rne(s * (1.f / (1.f + __expf(-s))));   // silu
  }
}

// ------- 3a: partial x_dbl GEMM: 8-way split over d; one pixel per thread ---
__global__ __launch_bounds__(256)
void xdbl_part_k(const unsigned short* __restrict__ xs, const float* __restrict__ xpw,
                 float* __restrict__ partial)
{
  __shared__ float sw[34 * 64];    // xpw chunk, [k][dd]
  int tid = threadIdx.x;
  int p  = blockIdx.x * 256 + tid;   // pixel 0..16383 (b*4096+l)
  int d0 = blockIdx.y * 64;
  int b = p >> 12, l = p & 4095;
  for (int i = tid; i < 34 * 64; i += 256) {
    int k = i >> 6, dd = i & 63;
    sw[i] = xpw[k * 512 + d0 + dd];
  }
  __syncthreads();
  float acc[34];
#pragma unroll
  for (int k = 0; k < 34; k++) acc[k] = 0.f;
  const unsigned short* xp = xs + (size_t)(b * 512 + d0) * 4096 + l;
#pragma unroll 4
  for (int dd = 0; dd < 64; dd++) {
    float v = b2f(xp[(size_t)dd * 4096]);
#pragma unroll
    for (int k = 0; k < 34; k++) acc[k] = fmaf(sw[k * 64 + dd], v, acc[k]);
  }
  float* op = partial + (size_t)blockIdx.y * 34 * 16384 + p;
#pragma unroll
  for (int k = 0; k < 34; k++) op[(size_t)k * 16384] = acc[k];
}

// ------- 3b: reduce 8 partials -> xdbl_r[34][16384] -------------------------
__global__ __launch_bounds__(256)
void xdbl_reduce_k(const float* __restrict__ partial, float* __restrict__ xdbl_r)
{
  int gid = blockIdx.x * 256 + threadIdx.x;   // 0 .. 34*16384-1
  float s = 0.f;
#pragma unroll
  for (int sp = 0; sp < 8; sp++) s += partial[(size_t)sp * 34 * 16384 + gid];
  xdbl_r[gid] = s;
}

// ------- 3c: dts -> softplus -> delta only (a, bb derived later in scan) ----
__global__ __launch_bounds__(256)
void delta_k(const float* __restrict__ xdbl_r, const float* __restrict__ dtw,
             const float* __restrict__ dtb, float* __restrict__ del)
{
  __shared__ float sm[32][256];    // dt-rank rows
  int tid = threadIdx.x;
  int l0 = blockIdx.x * 256;       // l tile within batch
  int d0 = blockIdx.y * 64;        // d chunk
  int b  = blockIdx.z;
  int p0 = b * 4096 + l0;
#pragma unroll
  for (int k = 0; k < 32; k++) sm[k][tid] = xdbl_r[k * 16384 + p0 + tid];
  __syncthreads();
#pragma unroll 2
  for (int dd = 0; dd < 64; dd++) {
    int d = d0 + dd;
    float s = dtb[d];
#pragma unroll
    for (int r = 0; r < 32; r++) s = fmaf(dtw[d * 32 + r], sm[r][tid], s);
    float delta = fmaxf(s, 0.f) + __logf(1.f + __expf(-fabsf(s)));  // softplus
    del[((size_t)(b * 512 + d) << 12) + l0 + tid] = delta;
  }
}

// ---- fused: a/bb on-the-fly + thread-serial(16)+wave scan + dilated convs --
// Each thread owns 16 contiguous l; a/b/xs in registers; bf16 ypre out.
__global__ __launch_bounds__(256)
void scan_sfconv_k(const float* __restrict__ del, const float* __restrict__ Bsr,
                   const unsigned short* __restrict__ xs, const float* __restrict__ A_logs,
                   const float* __restrict__ k1, const float* __restrict__ k2,
                   const float* __restrict__ k3, const float* __restrict__ alpha,
                   const float* __restrict__ Cs, const float* __restrict__ Ds,
                   unsigned short* __restrict__ ypre)
{
  __shared__ float t[64][65];      // h grid, conv source
  __shared__ float segA[4], segH[4];
  int plane = blockIdx.x;
  int d = plane & 511;
  int b = plane >> 9;
  int tid = threadIdx.x;
  int wave = tid >> 6, lane = tid & 63;
  size_t base = (size_t)plane * 4096;
  float Ad = -__expf(A_logs[d]);

  // load own 16 contiguous elements, build a/b, keep xs
  const int l0 = tid << 4;
  float a_reg[16], b_reg[16], x_reg[16];
  ushort8_t xv0 = *(const ushort8_t*)&xs[base + l0];
  ushort8_t xv1 = *(const ushort8_t*)&xs[base + l0 + 8];
#pragma unroll
  for (int j = 0; j < 8; ++j) {
    x_reg[j]     = b2f(xv0[j]);
    x_reg[8 + j] = b2f(xv1[j]);
  }
#pragma unroll
  for (int k = 0; k < 4; ++k) {
    float4 dv4 = *(const float4*)&del[base + l0 + k * 4];
    float4 bs4 = *(const float4*)&Bsr[(b << 12) + l0 + k * 4];
    float dv[4] = {dv4.x, dv4.y, dv4.z, dv4.w};
    float bs[4] = {bs4.x, bs4.y, bs4.z, bs4.w};
#pragma unroll
    for (int j = 0; j < 4; ++j) {
      a_reg[k * 4 + j] = __expf(dv[j] * Ad);
      b_reg[k * 4 + j] = dv[j] * bs[j] * x_reg[k * 4 + j];
    }
  }

  // serial compose of this thread's segment
  float A_th = a_reg[0], H_th = b_reg[0];
#pragma unroll
  for (int j = 1; j < 16; ++j) {
    H_th = fmaf(a_reg[j], H_th, b_reg[j]);
    A_th *= a_reg[j];
  }

  // wave-level inclusive scan over thread aggregates
#pragma unroll
  for (int off = 1; off < 64; off <<= 1) {
    float Ap = __shfl_up(A_th, off);
    float Hp = __shfl_up(H_th, off);
    if (lane >= off) { H_th = fmaf(A_th, Hp, H_th); A_th *= Ap; }
  }
  float eA = __shfl_up(A_th, 1);
  float eH = __shfl_up(H_th, 1);
  if (lane == 0) { eA = 1.f; eH = 0.f; }
  if (lane == 63) { segA[wave] = A_th; segH[wave] = H_th; }
  __syncthreads();

  float cy1 = segH[0];
  float cy2 = fmaf(segA[1], cy1, segH[1]);
  float cy3 = fmaf(segA[2], cy2, segH[2]);
  float myc = (wave == 1) ? cy1 : (wave == 2) ? cy2 : (wave == 3) ? cy3 : 0.f;
  float h = fmaf(eA, myc, eH);     // h entering this thread's segment

  // rewalk from registers, write h into LDS grid
  int row = tid >> 2, c0 = (tid & 3) << 4;
#pragma unroll
  for (int j = 0; j < 16; ++j) {
    h = fmaf(a_reg[j], h, b_reg[j]);
    t[row][c0 + j] = h;
  }
  __syncthreads();

  // 3 dilated edge-pad convs from LDS + y = conv*Cs + xs*Ds (own 16 elems)
  float wv[3][9];
  float a0 = alpha[0], a1 = alpha[1], a2 = alpha[2];
#pragma unroll
  for (int j = 0; j < 9; j++) {
    wv[0][j] = a0 * k1[d * 9 + j];
    wv[1][j] = a1 * k2[d * 9 + j];
    wv[2][j] = a2 * k3[d * 9 + j];
  }
  float Dv = Ds[d];
  float cs_reg[16];
#pragma unroll
  for (int k = 0; k < 4; ++k) {
    float4 c4 = *(const float4*)&Cs[(b << 12) + l0 + k * 4];
    cs_reg[k * 4 + 0] = c4.x; cs_reg[k * 4 + 1] = c4.y;
    cs_reg[k * 4 + 2] = c4.z; cs_reg[k * 4 + 3] = c4.w;
  }
  unsigned short ov[16];
  const int y = row;               // constant per thread
#pragma unroll
  for (int j = 0; j < 16; j++) {
    int x = c0 + j;
    float s = 0.f;
#pragma unroll
    for (int dil = 1; dil <= 3; dil++)
#pragma unroll
      for (int uu = 0; uu < 3; uu++)
#pragma unroll
        for (int vv = 0; vv < 3; vv++) {
          int yy = y + (uu - 1) * dil; yy = yy < 0 ? 0 : (yy > 63 ? 63 : yy);
          int xx = x + (vv - 1) * dil; xx = xx < 0 ? 0 : (xx > 63 ? 63 : xx);
          s = fmaf(wv[dil - 1][uu * 3 + vv], t[yy][xx], s);
        }
    ov[j] = bf16rne(fmaf(s, cs_reg[j], x_reg[j] * Dv));
  }
  ushort8_t o0, o1;
#pragma unroll
  for (int j = 0; j < 8; ++j) { o0[j] = ov[j]; o1[j] = ov[8 + j]; }
  *(ushort8_t*)&ypre[base + l0]     = o0;
  *(ushort8_t*)&ypre[base + l0 + 8] = o1;
}

// ---------------- bf16 transpose (B,D,L) -> (B,L,D) --------------------------
__global__ __launch_bounds__(256)
void transpose_bf16_k(const unsigned short* __restrict__ src,
                      unsigned short* __restrict__ dst)
{
  __shared__ unsigned short t[64][72];   // [l][d], pad 72
  int l0 = blockIdx.x * 64;
  int d0 = blockIdx.y * 64;
  int b  = blockIdx.z;
  int tid = threadIdx.x;
  int dl = tid & 63, lg0 = tid >> 6;
#pragma unroll
  for (int i = 0; i < 2; ++i) {
    int lg = lg0 + i * 4;                // l-chunk of 8
    ushort8_t v = *(const ushort8_t*)&src[(size_t)(b * 512 + d0 + dl) * 4096 + l0 + lg * 8];
#pragma unroll
    for (int j = 0; j < 8; ++j) t[lg * 8 + j][dl] = v[j];
  }
  __syncthreads();
  int pl = tid >> 2, c0 = (tid & 3) << 4;
  ushort8_t a = *(const ushort8_t*)&t[pl][c0];
  ushort8_t bb = *(const ushort8_t*)&t[pl][c0 + 8];
  size_t o = (size_t)(b * 4096 + l0 + pl) * 512 + d0 + c0;
  *(ushort8_t*)&dst[o] = a;
  *(ushort8_t*)&dst[o + 8] = bb;
}

// -------- LayerNorm over D + silu(z) gate, bf16 in/out ----------------------
__global__ __launch_bounds__(256)
void ln_silu_split_k(const unsigned short* __restrict__ y,
                     const unsigned short* __restrict__ z,
                     const float* __restrict__ lw, const float* __restrict__ lb,
                     unsigned short* __restrict__ hi)
{
  int wid = threadIdx.x >> 6, lane = threadIdx.x & 63;
  int pix = blockIdx.x * 4 + wid;            // 0..16383
  const unsigned short* yp = y + (size_t)pix * 512;
  const unsigned short* zp = z + (size_t)pix * 512;
  ushort8_t yv8 = *(const ushort8_t*)&yp[lane * 8];
  float vv[8];
#pragma unroll
  for (int j = 0; j < 8; j++) vv[j] = b2f(yv8[j]);
  float sum = 0.f;
#pragma unroll
  for (int j = 0; j < 8; j++) sum += vv[j];
#pragma unroll
  for (int off = 1; off < 64; off <<= 1) sum += __shfl_xor(sum, off);
  float mu = sum * (1.f / 512.f);
  float q = 0.f;
#pragma unroll
  for (int j = 0; j < 8; j++) { float dd = vv[j] - mu; q += dd * dd; }
#pragma unroll
  for (int off = 1; off < 64; off <<= 1) q += __shfl_xor(q, off);
  float rstd = rsqrtf(q * (1.f / 512.f) + 1e-5f);
  ushort8_t zv8 = *(const ushort8_t*)&zp[lane * 8];
  unsigned short oh[8];
#pragma unroll
  for (int j = 0; j < 8; j++) {
    int dch = lane * 8 + j;
    float val = (vv[j] - mu) * rstd * lw[dch] + lb[dch];
    float zv = b2f(zv8[j]);
    float ov = val * (zv * (1.f / (1.f + __expf(-zv))));
    oh[j] = bf16rne(ov);
  }
  size_t o = (size_t)pix * 512 + lane * 8;
  *(ushort4*)&hi[o]     = make_ushort4(oh[0], oh[1], oh[2], oh[3]);
  *(ushort4*)&hi[o + 4] = make_ushort4(oh[4], oh[5], oh[6], oh[7]);
}

extern "C" void kernel_launch(void* const* d_in, const int* in_sizes, int n_in,
                              void* d_out, int out_size, void* d_ws, size_t ws_size,
                              hipStream_t stream)
{
  const float* x    = (const float*)d_in[0];
  const float* win  = (const float*)d_in[1];
  const float* cw   = (const float*)d_in[2];
  const float* cb   = (const float*)d_in[3];
  const float* xpw  = (const float*)d_in[4];
  const float* dtw  = (const float*)d_in[5];
  const float* dtb  = (const float*)d_in[6];
  const float* alog = (const float*)d_in[7];
  const float* Dsv  = (const float*)d_in[8];
  const float* k1   = (const float*)d_in[9];
  const float* k2   = (const float*)d_in[10];
  const float* k3   = (const float*)d_in[11];
  const float* alp  = (const float*)d_in[12];
  const float* lw   = (const float*)d_in[13];
  const float* lb   = (const float*)d_in[14];
  const float* wout = (const float*)d_in[15];
  float* out = (float*)d_out;

  const size_t NP = (size_t)4 * 512 * 4096;   // 8,388,608 elems per (B,D,L) buffer
  float* ws = (float*)d_ws;
  float* xs     = ws;                 // Whi/Wlo -> xs bf16 -> y_t bf16 -> Ohi/Olo
  float* zbuf   = ws + NP;            // z bf16 (1st half) | ypre bf16 (2nd half)
  float* w4     = ws + 2 * NP;        // Ahi -> delta -> Yhi
  float* xdbl_r = ws + 3 * NP;        // 34 x 16384

  unsigned short* Ahi  = (unsigned short*)w4;        // 16384x512 bf16
  unsigned short* Whi  = (unsigned short*)xs;        // 1024x512 bf16
  unsigned short* Wlo  = Whi + (size_t)1024 * 512;
  unsigned short* xinb = (unsigned short*)d_out;     // xin bf16 (d_out scratch)
  unsigned short* xs16 = (unsigned short*)xs;        // xs bf16 (after Whi/Wlo dead)
  unsigned short* zb16 = (unsigned short*)zbuf;              // 16384x512 bf16
  unsigned short* yp16 = zb16 + (size_t)16384 * 512;         // ypre bf16
  unsigned short* yt16 = (unsigned short*)xs;        // y_t bf16 (xs16 dead)
  unsigned short* Yhi  = (unsigned short*)w4;        // after delta consumed
  unsigned short* Ohi  = (unsigned short*)xs;        // after y_t consumed
  unsigned short* Olo  = Ohi + (size_t)512 * 512;

  cvt_hi_k<<<8192, 256, 0, stream>>>(x, Ahi, 2097152);                      // x -> bf16
  split_k<<<512, 256, 0, stream>>>(win, Whi, Wlo, 131072);                  // win -> hi/lo
  gemm_mfma<0><<<1024, 256, 0, stream>>>(Ahi, Whi, Wlo, xinb, zb16);        // xin, z (bf16)
  conv_silu_k<<<2048, 256, 0, stream>>>(xinb, cw, cb, xs16);                // xs bf16
  xdbl_part_k<<<dim3(64, 8), 256, 0, stream>>>(xs16, xpw, out);             // partial->d_out
  xdbl_reduce_k<<<2176, 256, 0, stream>>>(out, xdbl_r);                     // xdbl_r
  delta_k<<<dim3(16, 8, 4), 256, 0, stream>>>(xdbl_r, dtw, dtb, w4);        // delta->w4
  scan_sfconv_k<<<2048, 256, 0, stream>>>(w4, xdbl_r + 32 * 16384, xs16, alog,
                                          k1, k2, k3, alp,
                                          xdbl_r + 33 * 16384, Dsv, yp16);  // ypre bf16
  transpose_bf16_k<<<dim3(64, 8, 4), 256, 0, stream>>>(yp16, yt16);         // y_t bf16
  ln_silu_split_k<<<4096, 256, 0, stream>>>(yt16, zb16, lw, lb, Yhi);       // y -> bf16
  split_k<<<256, 256, 0, stream>>>(wout, Ohi, Olo, 65536);                  // wout -> hi/lo
  gemm_mfma<1><<<512, 256, 0, stream>>>(Yhi, Ohi, Olo, out, nullptr);       // final
}

// Round 14
// 178.132 us; speedup vs baseline: 1.1080x; 1.1080x over previous
//
#include <hip/hip_runtime.h>
#include <cstddef>

// B=4, L=4096 (=64x64), d_model=512, d_inner=512, dt_rank=32, d_state=1
// GEMMs on MFMA: xin-half of in_proj = 2-term bf16 (A*(Whi+Wlo));
// z-half and out_proj = 1-term (pure bf16, error ~5e-4 << 1.68e-2 thr).
// kt-outer staging (48/32 KB LDS), XCD-chunked swizzle.
// bf16 intermediates: xin, z, ypre/y_t (xs stays fp32 — r13 showed no gain).
// scan_sfconv: thread-serial(16)+wave-scan; xs in regs; bf16 ypre out.

typedef __attribute__((ext_vector_type(8))) short short8;
typedef __attribute__((ext_vector_type(8))) unsigned short ushort8_t;
typedef __attribute__((ext_vector_type(4))) float f32x4;

__device__ __forceinline__ void gload16(const void* g, void* l) {
  __builtin_amdgcn_global_load_lds(
      (const __attribute__((address_space(1))) void*)g,
      (__attribute__((address_space(3))) void*)l, 16, 0, 0);
}

__device__ __forceinline__ void bf16split(float v, unsigned short& h, unsigned short& l) {
  unsigned u = __float_as_uint(v);
  unsigned uh = (u + 0x7fffu + ((u >> 16) & 1u)) & 0xffff0000u;
  h = (unsigned short)(uh >> 16);
  float rem = v - __uint_as_float(uh);
  unsigned ur = __float_as_uint(rem);
  l = (unsigned short)((ur + 0x7fffu + ((ur >> 16) & 1u)) >> 16);
}

__device__ __forceinline__ unsigned short bf16rne(float v) {
  unsigned u = __float_as_uint(v);
  return (unsigned short)((u + 0x7fffu + ((u >> 16) & 1u)) >> 16);
}

__device__ __forceinline__ float b2f(unsigned short u) {
  return __uint_as_float((unsigned)u << 16);
}

// ---------------- fp32 -> bf16 hi/lo split (in_proj weights) ----------------
__global__ __launch_bounds__(256)
void split_k(const float* __restrict__ in, unsigned short* __restrict__ hi,
             unsigned short* __restrict__ lo, int n4)
{
  int i = blockIdx.x * 256 + threadIdx.x;
  if (i >= n4) return;
  float4 v = ((const float4*)in)[i];
  float vv[4] = {v.x, v.y, v.z, v.w};
  unsigned short h[4], l[4];
#pragma unroll
  for (int j = 0; j < 4; ++j) bf16split(vv[j], h[j], l[j]);
  ((ushort4*)hi)[i] = make_ushort4(h[0], h[1], h[2], h[3]);
  ((ushort4*)lo)[i] = make_ushort4(l[0], l[1], l[2], l[3]);
}

// ---------------- fp32 -> bf16 RNE ------------------------------------------
__global__ __launch_bounds__(256)
void cvt_hi_k(const float* __restrict__ in, unsigned short* __restrict__ hi, int n4)
{
  int i = blockIdx.x * 256 + threadIdx.x;
  if (i >= n4) return;
  float4 v = ((const float4*)in)[i];
  ((ushort4*)hi)[i] = make_ushort4(bf16rne(v.x), bf16rne(v.y), bf16rne(v.z), bf16rne(v.w));
}

// ---------------- bf16 MFMA GEMM --------------------------------------------
// 128x128 tile, 4 waves (2x2 of 64x64), 16x16x32 MFMA, BK=64, K=512.
// MODE0: xin-half 2-term (Whi+Wlo), z-half 1-term. MODE1: 1-term, 32 KB LDS.
template<int MODE>
__global__ __launch_bounds__(256)
void gemm_mfma(const unsigned short* __restrict__ Ag_, const unsigned short* __restrict__ Whi,
               const unsigned short* __restrict__ Wlo,
               void* __restrict__ o1v, void* __restrict__ o2v)
{
  __shared__ char smem[(MODE == 1) ? 32768 : 49152];
  unsigned short* sA  = (unsigned short*)smem;
  unsigned short* sBh = (unsigned short*)(smem + 16384);
  unsigned short* sBl = (unsigned short*)(MODE == 1 ? smem : smem + 32768); // unused if !two
  const int tid = threadIdx.x;
  const int wave = tid >> 6, lane = tid & 63;

  const int nwg = gridDim.x;
  const int q = nwg >> 3, r = nwg & 7;
  const int xcd = blockIdx.x & 7, wi = blockIdx.x >> 3;
  const int logical = (xcd < r ? xcd * (q + 1) : r * (q + 1) + (xcd - r) * q) + wi;
  const int NTN = (MODE == 0) ? 8 : 4;
  const int tm = logical / NTN, tn = logical - tm * NTN;
  const int m0 = tm << 7, n0 = tn << 7;
  // 2nd term (Wlo) only for the xin half of in_proj.
  const bool two = (MODE == 0) && (n0 < 512);

  const int wm = (wave & 1) << 6;
  const int wn = (wave >> 1) << 6;
  const int q16 = (lane >> 4) << 4;
  const int l15 = lane & 15;

  int srow[4], scol[4];
#pragma unroll
  for (int c = 0; c < 4; ++c) {
    int o = (wave << 12) + (c << 10) + (lane << 4);
    int row = o >> 7;
    srow[c] = row;
    scol[c] = (o & 127) ^ ((row & 7) << 4);
  }

  f32x4 acc[4][4];
#pragma unroll
  for (int i = 0; i < 4; ++i)
#pragma unroll
    for (int j = 0; j < 4; ++j) acc[i][j] = (f32x4){0.f, 0.f, 0.f, 0.f};

  for (int kt = 0; kt < 8; ++kt) {
    int kb = kt << 7;
    __syncthreads();
#pragma unroll
    for (int c = 0; c < 4; ++c) {
      size_t ga = (size_t)(m0 + srow[c]) * 1024 + kb + scol[c];
      size_t gb = (size_t)(n0 + srow[c]) * 1024 + kb + scol[c];
      int lo_ = (wave << 12) + (c << 10);
      gload16((const char*)Ag_ + ga, (char*)sA + lo_);
      gload16((const char*)Whi + gb, (char*)sBh + lo_);
      if (two) gload16((const char*)Wlo + gb, (char*)sBl + lo_);
    }
    __syncthreads();
#pragma unroll
    for (int ks = 0; ks < 2; ++ks) {
      short8 af[4], bh[4], bl[4];
#pragma unroll
      for (int i = 0; i < 4; ++i) {
        int row = wm + (i << 4) + l15;
        int cb = ((ks << 6) + q16) ^ ((row & 7) << 4);
        af[i] = *(const short8*)((const char*)sA + (row << 7) + cb);
      }
#pragma unroll
      for (int j = 0; j < 4; ++j) {
        int row = wn + (j << 4) + l15;
        int cb = ((ks << 6) + q16) ^ ((row & 7) << 4);
        bh[j] = *(const short8*)((const char*)sBh + (row << 7) + cb);
        if (two) bl[j] = *(const short8*)((const char*)sBl + (row << 7) + cb);
      }
#pragma unroll
      for (int i = 0; i < 4; ++i)
#pragma unroll
        for (int j = 0; j < 4; ++j) {
          acc[i][j] = __builtin_amdgcn_mfma_f32_16x16x32_bf16(af[i], bh[j], acc[i][j], 0, 0, 0);
          if (two)
            acc[i][j] = __builtin_amdgcn_mfma_f32_16x16x32_bf16(af[i], bl[j], acc[i][j], 0, 0, 0);
        }
    }
  }

  if (MODE == 0) {
    unsigned short* xinb = (unsigned short*)o1v;
    unsigned short* zb16 = (unsigned short*)o2v;
    const int mb_base = m0 + wm + ((lane >> 4) << 2);
#pragma unroll
    for (int j = 0; j < 4; ++j) {
      int n = n0 + wn + (j << 4) + l15;
#pragma unroll
      for (int i = 0; i < 4; ++i) {
        int mb = mb_base + (i << 4);
        if (n < 512) {
          int b = mb >> 12, l = mb & 4095;
          ushort4 hv = make_ushort4(bf16rne(acc[i][j][0]), bf16rne(acc[i][j][1]),
                                    bf16rne(acc[i][j][2]), bf16rne(acc[i][j][3]));
          *(ushort4*)&xinb[((size_t)(b * 512 + n) << 12) + l] = hv;
        } else {
#pragma unroll
          for (int rr = 0; rr < 4; ++rr)
            zb16[(size_t)(mb + rr) * 512 + (n - 512)] = bf16rne(acc[i][j][rr]);
        }
      }
    }
  } else {
    float* o1 = (float*)o1v;
    // stage C tile through LDS in two 64x128 halves; store coalesced float4
    float* sC = (float*)smem;           // 64 x 128 fp32 = 32 KB
    const int i_base = (lane >> 4) << 2;
#pragma unroll
    for (int half = 0; half < 2; ++half) {
      __syncthreads();
      if ((wave & 1) == half) {
#pragma unroll
        for (int j = 0; j < 4; ++j) {
          int nl = wn + (j << 4) + l15;
#pragma unroll
          for (int i = 0; i < 4; ++i) {
            int mloc = (i << 4) + i_base;
#pragma unroll
            for (int rr = 0; rr < 4; ++rr)
              sC[(mloc + rr) * 128 + nl] = acc[i][j][rr];
          }
        }
      }
      __syncthreads();
      int cx = (tid & 31) << 2;
      int r0 = tid >> 5;
#pragma unroll
      for (int it = 0; it < 8; ++it) {
        int row = r0 + (it << 3);
        *(float4*)&o1[(size_t)(m0 + (half << 6) + row) * 512 + n0 + cx] =
            *(float4*)&sC[row * 128 + cx];
      }
    }
  }
}

// -------- depthwise 3x3 SAME (zero pad) + bias + silu, bf16 in, fp32 out ----
__global__ __launch_bounds__(256)
void conv_silu_k(const unsigned short* __restrict__ xin, const float* __restrict__ w,
                 const float* __restrict__ bias, float* __restrict__ xs)
{
  __shared__ float t[64][65];
  int plane = blockIdx.x;          // b*512 + d
  int d = plane & 511;
  int tid = threadIdx.x;
  const unsigned short* src = xin + (size_t)plane * 4096;
  int l0 = tid << 4, row = tid >> 2, c0 = (tid & 3) << 4;
  ushort8_t v0 = *(const ushort8_t*)&src[l0];
  ushort8_t v1 = *(const ushort8_t*)&src[l0 + 8];
#pragma unroll
  for (int j = 0; j < 8; ++j) {
    t[row][c0 + j]     = b2f(v0[j]);
    t[row][c0 + 8 + j] = b2f(v1[j]);
  }
  float wv[9];
#pragma unroll
  for (int j = 0; j < 9; j++) wv[j] = w[d * 9 + j];
  float bv = bias[d];
  __syncthreads();
  float* dst = xs + (size_t)plane * 4096;
#pragma unroll
  for (int i = 0; i < 16; i++) {
    int idx = tid + i * 256;
    int y = idx >> 6, x = idx & 63;
    float s = bv;
#pragma unroll
    for (int u = 0; u < 3; u++)
#pragma unroll
      for (int v = 0; v < 3; v++) {
        int yy = y + u - 1, xx = x + v - 1;
        if (yy >= 0 && yy < 64 && xx >= 0 && xx < 64)
          s = fmaf(wv[u * 3 + v], t[yy][xx], s);
      }
    dst[idx] = s * (1.f / (1.f + __expf(-s)));   // silu
  }
}

// ------- 3a: partial x_dbl GEMM: 8-way split over d; one pixel per thread ---
__global__ __launch_bounds__(256)
void xdbl_part_k(const float* __restrict__ xs, const float* __restrict__ xpw,
                 float* __restrict__ partial)
{
  __shared__ float sw[34 * 64];    // xpw chunk, [k][dd]
  int tid = threadIdx.x;
  int p  = blockIdx.x * 256 + tid;   // pixel 0..16383 (b*4096+l)
  int d0 = blockIdx.y * 64;
  int b = p >> 12, l = p & 4095;
  for (int i = tid; i < 34 * 64; i += 256) {
    int k = i >> 6, dd = i & 63;
    sw[i] = xpw[k * 512 + d0 + dd];
  }
  __syncthreads();
  float acc[34];
#pragma unroll
  for (int k = 0; k < 34; k++) acc[k] = 0.f;
  const float* xp = xs + (size_t)(b * 512 + d0) * 4096 + l;
#pragma unroll 4
  for (int dd = 0; dd < 64; dd++) {
    float v = xp[(size_t)dd * 4096];
#pragma unroll
    for (int k = 0; k < 34; k++) acc[k] = fmaf(sw[k * 64 + dd], v, acc[k]);
  }
  float* op = partial + (size_t)blockIdx.y * 34 * 16384 + p;
#pragma unroll
  for (int k = 0; k < 34; k++) op[(size_t)k * 16384] = acc[k];
}

// ------- 3b: reduce 8 partials -> xdbl_r[34][16384] -------------------------
__global__ __launch_bounds__(256)
void xdbl_reduce_k(const float* __restrict__ partial, float* __restrict__ xdbl_r)
{
  int gid = blockIdx.x * 256 + threadIdx.x;   // 0 .. 34*16384-1
  float s = 0.f;
#pragma unroll
  for (int sp = 0; sp < 8; sp++) s += partial[(size_t)sp * 34 * 16384 + gid];
  xdbl_r[gid] = s;
}

// ------- 3c: dts -> softplus -> delta only ----------------------------------
__global__ __launch_bounds__(256)
void delta_k(const float* __restrict__ xdbl_r, const float* __restrict__ dtw,
             const float* __restrict__ dtb, float* __restrict__ del)
{
  __shared__ float sm[32][256];    // dt-rank rows
  int tid = threadIdx.x;
  int l0 = blockIdx.x * 256;       // l tile within batch
  int d0 = blockIdx.y * 64;        // d chunk
  int b  = blockIdx.z;
  int p0 = b * 4096 + l0;
#pragma unroll
  for (int k = 0; k < 32; k++) sm[k][tid] = xdbl_r[k * 16384 + p0 + tid];
  __syncthreads();
#pragma unroll 2
  for (int dd = 0; dd < 64; dd++) {
    int d = d0 + dd;
    float s = dtb[d];
#pragma unroll
    for (int r = 0; r < 32; r++) s = fmaf(dtw[d * 32 + r], sm[r][tid], s);
    float delta = fmaxf(s, 0.f) + __logf(1.f + __expf(-fabsf(s)));  // softplus
    del[((size_t)(b * 512 + d) << 12) + l0 + tid] = delta;
  }
}

// ---- fused: a/bb on-the-fly + thread-serial(16)+wave scan + dilated convs --
__global__ __launch_bounds__(256)
void scan_sfconv_k(const float* __restrict__ del, const float* __restrict__ Bsr,
                   const float* __restrict__ xs, const float* __restrict__ A_logs,
                   const float* __restrict__ k1, const float* __restrict__ k2,
                   const float* __restrict__ k3, const float* __restrict__ alpha,
                   const float* __restrict__ Cs, const float* __restrict__ Ds,
                   unsigned short* __restrict__ ypre)
{
  __shared__ float t[64][65];      // h grid, conv source
  __shared__ float segA[4], segH[4];
  int plane = blockIdx.x;
  int d = plane & 511;
  int b = plane >> 9;
  int tid = threadIdx.x;
  int wave = tid >> 6, lane = tid & 63;
  size_t base = (size_t)plane * 4096;
  float Ad = -__expf(A_logs[d]);

  // load own 16 contiguous elements, build a/b, keep xs
  const int l0 = tid << 4;
  float a_reg[16], b_reg[16], x_reg[16];
#pragma unroll
  for (int k = 0; k < 4; ++k) {
    float4 dv4 = *(const float4*)&del[base + l0 + k * 4];
    float4 bs4 = *(const float4*)&Bsr[(b << 12) + l0 + k * 4];
    float4 xs4 = *(const float4*)&xs[base + l0 + k * 4];
    float dv[4] = {dv4.x, dv4.y, dv4.z, dv4.w};
    float bs[4] = {bs4.x, bs4.y, bs4.z, bs4.w};
    float xv[4] = {xs4.x, xs4.y, xs4.z, xs4.w};
#pragma unroll
    for (int j = 0; j < 4; ++j) {
      a_reg[k * 4 + j] = __expf(dv[j] * Ad);
      b_reg[k * 4 + j] = dv[j] * bs[j] * xv[j];
      x_reg[k * 4 + j] = xv[j];
    }
  }

  // serial compose of this thread's segment
  float A_th = a_reg[0], H_th = b_reg[0];
#pragma unroll
  for (int j = 1; j < 16; ++j) {
    H_th = fmaf(a_reg[j], H_th, b_reg[j]);
    A_th *= a_reg[j];
  }

  // wave-level inclusive scan over thread aggregates
#pragma unroll
  for (int off = 1; off < 64; off <<= 1) {
    float Ap = __shfl_up(A_th, off);
    float Hp = __shfl_up(H_th, off);
    if (lane >= off) { H_th = fmaf(A_th, Hp, H_th); A_th *= Ap; }
  }
  float eA = __shfl_up(A_th, 1);
  float eH = __shfl_up(H_th, 1);
  if (lane == 0) { eA = 1.f; eH = 0.f; }
  if (lane == 63) { segA[wave] = A_th; segH[wave] = H_th; }
  __syncthreads();

  float cy1 = segH[0];
  float cy2 = fmaf(segA[1], cy1, segH[1]);
  float cy3 = fmaf(segA[2], cy2, segH[2]);
  float myc = (wave == 1) ? cy1 : (wave == 2) ? cy2 : (wave == 3) ? cy3 : 0.f;
  float h = fmaf(eA, myc, eH);     // h entering this thread's segment

  // rewalk from registers, write h into LDS grid
  int row = tid >> 2, c0 = (tid & 3) << 4;
#pragma unroll
  for (int j = 0; j < 16; ++j) {
    h = fmaf(a_reg[j], h, b_reg[j]);
    t[row][c0 + j] = h;
  }
  __syncthreads();

  // 3 dilated edge-pad convs from LDS + y = conv*Cs + xs*Ds (own 16 elems)
  float wv[3][9];
  float a0 = alpha[0], a1 = alpha[1], a2 = alpha[2];
#pragma unroll
  for (int j = 0; j < 9; j++) {
    wv[0][j] = a0 * k1[d * 9 + j];
    wv[1][j] = a1 * k2[d * 9 + j];
    wv[2][j] = a2 * k3[d * 9 + j];
  }
  float Dv = Ds[d];
  float cs_reg[16];
#pragma unroll
  for (int k = 0; k < 4; ++k) {
    float4 c4 = *(const float4*)&Cs[(b << 12) + l0 + k * 4];
    cs_reg[k * 4 + 0] = c4.x; cs_reg[k * 4 + 1] = c4.y;
    cs_reg[k * 4 + 2] = c4.z; cs_reg[k * 4 + 3] = c4.w;
  }
  unsigned short ov[16];
  const int y = row;               // constant per thread
#pragma unroll
  for (int j = 0; j < 16; j++) {
    int x = c0 + j;
    float s = 0.f;
#pragma unroll
    for (int dil = 1; dil <= 3; dil++)
#pragma unroll
      for (int uu = 0; uu < 3; uu++)
#pragma unroll
        for (int vv = 0; vv < 3; vv++) {
          int yy = y + (uu - 1) * dil; yy = yy < 0 ? 0 : (yy > 63 ? 63 : yy);
          int xx = x + (vv - 1) * dil; xx = xx < 0 ? 0 : (xx > 63 ? 63 : xx);
          s = fmaf(wv[dil - 1][uu * 3 + vv], t[yy][xx], s);
        }
    ov[j] = bf16rne(fmaf(s, cs_reg[j], x_reg[j] * Dv));
  }
  ushort8_t o0, o1;
#pragma unroll
  for (int j = 0; j < 8; ++j) { o0[j] = ov[j]; o1[j] = ov[8 + j]; }
  *(ushort8_t*)&ypre[base + l0]     = o0;
  *(ushort8_t*)&ypre[base + l0 + 8] = o1;
}

// ---------------- bf16 transpose (B,D,L) -> (B,L,D) --------------------------
__global__ __launch_bounds__(256)
void transpose_bf16_k(const unsigned short* __restrict__ src,
                      unsigned short* __restrict__ dst)
{
  __shared__ unsigned short t[64][72];   // [l][d], pad 72
  int l0 = blockIdx.x * 64;
  int d0 = blockIdx.y * 64;
  int b  = blockIdx.z;
  int tid = threadIdx.x;
  int dl = tid & 63, lg0 = tid >> 6;
#pragma unroll
  for (int i = 0; i < 2; ++i) {
    int lg = lg0 + i * 4;                // l-chunk of 8
    ushort8_t v = *(const ushort8_t*)&src[(size_t)(b * 512 + d0 + dl) * 4096 + l0 + lg * 8];
#pragma unroll
    for (int j = 0; j < 8; ++j) t[lg * 8 + j][dl] = v[j];
  }
  __syncthreads();
  int pl = tid >> 2, c0 = (tid & 3) << 4;
  ushort8_t a = *(const ushort8_t*)&t[pl][c0];
  ushort8_t bb = *(const ushort8_t*)&t[pl][c0 + 8];
  size_t o = (size_t)(b * 4096 + l0 + pl) * 512 + d0 + c0;
  *(ushort8_t*)&dst[o] = a;
  *(ushort8_t*)&dst[o + 8] = bb;
}

// -------- LayerNorm over D + silu(z) gate, bf16 in/out ----------------------
__global__ __launch_bounds__(256)
void ln_silu_split_k(const unsigned short* __restrict__ y,
                     const unsigned short* __restrict__ z,
                     const float* __restrict__ lw, const float* __restrict__ lb,
                     unsigned short* __restrict__ hi)
{
  int wid = threadIdx.x >> 6, lane = threadIdx.x & 63;
  int pix = blockIdx.x * 4 + wid;            // 0..16383
  const unsigned short* yp = y + (size_t)pix * 512;
  const unsigned short* zp = z + (size_t)pix * 512;
  ushort8_t yv8 = *(const ushort8_t*)&yp[lane * 8];
  float vv[8];
#pragma unroll
  for (int j = 0; j < 8; j++) vv[j] = b2f(yv8[j]);
  float sum = 0.f;
#pragma unroll
  for (int j = 0; j < 8; j++) sum += vv[j];
#pragma unroll
  for (int off = 1; off < 64; off <<= 1) sum += __shfl_xor(sum, off);
  float mu = sum * (1.f / 512.f);
  float q = 0.f;
#pragma unroll
  for (int j = 0; j < 8; j++) { float dd = vv[j] - mu; q += dd * dd; }
#pragma unroll
  for (int off = 1; off < 64; off <<= 1) q += __shfl_xor(q, off);
  float rstd = rsqrtf(q * (1.f / 512.f) + 1e-5f);
  ushort8_t zv8 = *(const ushort8_t*)&zp[lane * 8];
  unsigned short oh[8];
#pragma unroll
  for (int j = 0; j < 8; j++) {
    int dch = lane * 8 + j;
    float val = (vv[j] - mu) * rstd * lw[dch] + lb[dch];
    float zv = b2f(zv8[j]);
    float ov = val * (zv * (1.f / (1.f + __expf(-zv))));
    oh[j] = bf16rne(ov);
  }
  size_t o = (size_t)pix * 512 + lane * 8;
  *(ushort4*)&hi[o]     = make_ushort4(oh[0], oh[1], oh[2], oh[3]);
  *(ushort4*)&hi[o + 4] = make_ushort4(oh[4], oh[5], oh[6], oh[7]);
}

extern "C" void kernel_launch(void* const* d_in, const int* in_sizes, int n_in,
                              void* d_out, int out_size, void* d_ws, size_t ws_size,
                              hipStream_t stream)
{
  const float* x    = (const float*)d_in[0];
  const float* win  = (const float*)d_in[1];
  const float* cw   = (const float*)d_in[2];
  const float* cb   = (const float*)d_in[3];
  const float* xpw  = (const float*)d_in[4];
  const float* dtw  = (const float*)d_in[5];
  const float* dtb  = (const float*)d_in[6];
  const float* alog = (const float*)d_in[7];
  const float* Dsv  = (const float*)d_in[8];
  const float* k1   = (const float*)d_in[9];
  const float* k2   = (const float*)d_in[10];
  const float* k3   = (const float*)d_in[11];
  const float* alp  = (const float*)d_in[12];
  const float* lw   = (const float*)d_in[13];
  const float* lb   = (const float*)d_in[14];
  const float* wout = (const float*)d_in[15];
  float* out = (float*)d_out;

  const size_t NP = (size_t)4 * 512 * 4096;   // 8,388,608 elems per (B,D,L) buffer
  float* ws = (float*)d_ws;
  float* xs     = ws;                 // Whi/Wlo -> xs fp32 -> y_t bf16 -> Ohi
  float* zbuf   = ws + NP;            // z bf16 (1st half) | ypre bf16 (2nd half)
  float* w4     = ws + 2 * NP;        // Ahi -> delta -> Yhi
  float* xdbl_r = ws + 3 * NP;        // 34 x 16384

  unsigned short* Ahi  = (unsigned short*)w4;        // 16384x512 bf16
  unsigned short* Whi  = (unsigned short*)xs;        // 1024x512 bf16
  unsigned short* Wlo  = Whi + (size_t)1024 * 512;
  unsigned short* xinb = (unsigned short*)d_out;     // xin bf16 (d_out scratch)
  unsigned short* zb16 = (unsigned short*)zbuf;              // 16384x512 bf16
  unsigned short* yp16 = zb16 + (size_t)16384 * 512;         // ypre bf16
  unsigned short* yt16 = (unsigned short*)xs;        // y_t bf16 (xs dead)
  unsigned short* Yhi  = (unsigned short*)w4;        // after delta consumed
  unsigned short* Ohi  = (unsigned short*)xs;        // after y_t consumed
  float* xsf = xs;                                   // xs fp32 view

  cvt_hi_k<<<8192, 256, 0, stream>>>(x, Ahi, 2097152);                      // x -> bf16
  split_k<<<512, 256, 0, stream>>>(win, Whi, Wlo, 131072);                  // win -> hi/lo
  gemm_mfma<0><<<1024, 256, 0, stream>>>(Ahi, Whi, Wlo, xinb, zb16);        // xin, z (bf16)
  conv_silu_k<<<2048, 256, 0, stream>>>(xinb, cw, cb, xsf);                 // xs fp32
  xdbl_part_k<<<dim3(64, 8), 256, 0, stream>>>(xsf, xpw, out);              // partial->d_out
  xdbl_reduce_k<<<2176, 256, 0, stream>>>(out, xdbl_r);                     // xdbl_r
  delta_k<<<dim3(16, 8, 4), 256, 0, stream>>>(xdbl_r, dtw, dtb, w4);        // delta->w4
  scan_sfconv_k<<<2048, 256, 0, stream>>>(w4, xdbl_r + 32 * 16384, xsf, alog,
                                          k1, k2, k3, alp,
                                          xdbl_r + 33 * 16384, Dsv, yp16);  // ypre bf16
  transpose_bf16_k<<<dim3(64, 8, 4), 256, 0, stream>>>(yp16, yt16);         // y_t bf16
  ln_silu_split_k<<<4096, 256, 0, stream>>>(yt16, zb16, lw, lb, Yhi);       // y -> bf16
  cvt_hi_k<<<256, 256, 0, stream>>>(wout, Ohi, 65536);                      // wout -> bf16
  gemm_mfma<1><<<512, 256, 0, stream>>>(Yhi, Ohi, Ohi, out, nullptr);       // final 1-term
}

// Round 15
// 177.796 us; speedup vs baseline: 1.1101x; 1.0019x over previous
//
#include <hip/hip_runtime.h>
#include <cstddef>

// B=4, L=4096 (=64x64), d_model=512, d_inner=512, dt_rank=32, d_state=1
// gemm0: 256x128 tile (2x work per barrier-step, latency amortization),
//   xin-half 2-term bf16 (A*(Whi+Wlo)), z-half 1-term. 64 KB LDS, 2 blk/CU.
// gemm1: 128x128 1-term (r14 config, 32 KB LDS).
// bf16 intermediates: xin, z, ypre/y_t. scan: thread-serial(16)+wave-scan.

typedef __attribute__((ext_vector_type(8))) short short8;
typedef __attribute__((ext_vector_type(8))) unsigned short ushort8_t;
typedef __attribute__((ext_vector_type(4))) float f32x4;

__device__ __forceinline__ void gload16(const void* g, void* l) {
  __builtin_amdgcn_global_load_lds(
      (const __attribute__((address_space(1))) void*)g,
      (__attribute__((address_space(3))) void*)l, 16, 0, 0);
}

__device__ __forceinline__ void bf16split(float v, unsigned short& h, unsigned short& l) {
  unsigned u = __float_as_uint(v);
  unsigned uh = (u + 0x7fffu + ((u >> 16) & 1u)) & 0xffff0000u;
  h = (unsigned short)(uh >> 16);
  float rem = v - __uint_as_float(uh);
  unsigned ur = __float_as_uint(rem);
  l = (unsigned short)((ur + 0x7fffu + ((ur >> 16) & 1u)) >> 16);
}

__device__ __forceinline__ unsigned short bf16rne(float v) {
  unsigned u = __float_as_uint(v);
  return (unsigned short)((u + 0x7fffu + ((u >> 16) & 1u)) >> 16);
}

__device__ __forceinline__ float b2f(unsigned short u) {
  return __uint_as_float((unsigned)u << 16);
}

// ---------------- fp32 -> bf16 hi/lo split (in_proj weights) ----------------
__global__ __launch_bounds__(256)
void split_k(const float* __restrict__ in, unsigned short* __restrict__ hi,
             unsigned short* __restrict__ lo, int n4)
{
  int i = blockIdx.x * 256 + threadIdx.x;
  if (i >= n4) return;
  float4 v = ((const float4*)in)[i];
  float vv[4] = {v.x, v.y, v.z, v.w};
  unsigned short h[4], l[4];
#pragma unroll
  for (int j = 0; j < 4; ++j) bf16split(vv[j], h[j], l[j]);
  ((ushort4*)hi)[i] = make_ushort4(h[0], h[1], h[2], h[3]);
  ((ushort4*)lo)[i] = make_ushort4(l[0], l[1], l[2], l[3]);
}

// ---------------- fp32 -> bf16 RNE ------------------------------------------
__global__ __launch_bounds__(256)
void cvt_hi_k(const float* __restrict__ in, unsigned short* __restrict__ hi, int n4)
{
  int i = blockIdx.x * 256 + threadIdx.x;
  if (i >= n4) return;
  float4 v = ((const float4*)in)[i];
  ((ushort4*)hi)[i] = make_ushort4(bf16rne(v.x), bf16rne(v.y), bf16rne(v.z), bf16rne(v.w));
}

// ---------------- gemm0: 256x128 tile, dual bf16 output ---------------------
// 4 waves as 2m x 2n (each 128m x 64n), 16x16x32 MFMA, BK=64, K=512.
// xin-half (n0<512): 2-term A*(Whi+Wlo); z-half: 1-term.
__global__ __launch_bounds__(256, 2)
void gemm0_k(const unsigned short* __restrict__ Ahi, const unsigned short* __restrict__ Whi,
             const unsigned short* __restrict__ Wlo,
             unsigned short* __restrict__ xinb, unsigned short* __restrict__ zb16)
{
  __shared__ char smem[65536];
  unsigned short* sA  = (unsigned short*)smem;            // 256 x 64 bf16 = 32 KB
  unsigned short* sBh = (unsigned short*)(smem + 32768);  // 128 x 64 = 16 KB
  unsigned short* sBl = (unsigned short*)(smem + 49152);  // 128 x 64 = 16 KB
  const int tid = threadIdx.x;
  const int wave = tid >> 6, lane = tid & 63;

  const int nwg = gridDim.x;                // 512
  const int q = nwg >> 3, r = nwg & 7;
  const int xcd = blockIdx.x & 7, wi = blockIdx.x >> 3;
  const int logical = (xcd < r ? xcd * (q + 1) : r * (q + 1) + (xcd - r) * q) + wi;
  const int tm = logical >> 3, tn = logical & 7;
  const int m0 = tm << 8;                   // 256-row tiles (within one b: 4096/256=16)
  const int n0 = tn << 7;
  const bool two = (n0 < 512);

  const int wm = (wave & 1) << 7;           // 0 / 128
  const int wn = (wave >> 1) << 6;          // 0 / 64
  const int q16 = (lane >> 4) << 4;
  const int l15 = lane & 15;

  int srA[8], scA[8];
#pragma unroll
  for (int c = 0; c < 8; ++c) {
    int o = (wave << 13) + (c << 10) + (lane << 4);
    int row = o >> 7;
    srA[c] = row;
    scA[c] = (o & 127) ^ ((row & 7) << 4);
  }
  int srB[4], scB[4];
#pragma unroll
  for (int c = 0; c < 4; ++c) {
    int o = (wave << 12) + (c << 10) + (lane << 4);
    int row = o >> 7;
    srB[c] = row;
    scB[c] = (o & 127) ^ ((row & 7) << 4);
  }

  f32x4 acc[8][4];
#pragma unroll
  for (int i = 0; i < 8; ++i)
#pragma unroll
    for (int j = 0; j < 4; ++j) acc[i][j] = (f32x4){0.f, 0.f, 0.f, 0.f};

  for (int kt = 0; kt < 8; ++kt) {
    int kb = kt << 7;
    __syncthreads();
#pragma unroll
    for (int c = 0; c < 8; ++c)
      gload16((const char*)Ahi + (size_t)(m0 + srA[c]) * 1024 + kb + scA[c],
              (char*)sA + (wave << 13) + (c << 10));
#pragma unroll
    for (int c = 0; c < 4; ++c) {
      size_t gb = (size_t)(n0 + srB[c]) * 1024 + kb + scB[c];
      int lo_ = (wave << 12) + (c << 10);
      gload16((const char*)Whi + gb, (char*)sBh + lo_);
      if (two) gload16((const char*)Wlo + gb, (char*)sBl + lo_);
    }
    __syncthreads();
#pragma unroll
    for (int ks = 0; ks < 2; ++ks) {
      short8 af[8], bh[4], bl[4];
#pragma unroll
      for (int i = 0; i < 8; ++i) {
        int row = wm + (i << 4) + l15;
        int cb = ((ks << 6) + q16) ^ ((row & 7) << 4);
        af[i] = *(const short8*)((const char*)sA + (row << 7) + cb);
      }
#pragma unroll
      for (int j = 0; j < 4; ++j) {
        int row = wn + (j << 4) + l15;
        int cb = ((ks << 6) + q16) ^ ((row & 7) << 4);
        bh[j] = *(const short8*)((const char*)sBh + (row << 7) + cb);
        if (two) bl[j] = *(const short8*)((const char*)sBl + (row << 7) + cb);
      }
#pragma unroll
      for (int i = 0; i < 8; ++i)
#pragma unroll
        for (int j = 0; j < 4; ++j) {
          acc[i][j] = __builtin_amdgcn_mfma_f32_16x16x32_bf16(af[i], bh[j], acc[i][j], 0, 0, 0);
          if (two)
            acc[i][j] = __builtin_amdgcn_mfma_f32_16x16x32_bf16(af[i], bl[j], acc[i][j], 0, 0, 0);
        }
    }
  }

  const int mb_base = m0 + wm + ((lane >> 4) << 2);
#pragma unroll
  for (int j = 0; j < 4; ++j) {
    int n = n0 + wn + (j << 4) + l15;
#pragma unroll
    for (int i = 0; i < 8; ++i) {
      int mb = mb_base + (i << 4);
      if (n < 512) {
        int b = mb >> 12, l = mb & 4095;
        ushort4 hv = make_ushort4(bf16rne(acc[i][j][0]), bf16rne(acc[i][j][1]),
                                  bf16rne(acc[i][j][2]), bf16rne(acc[i][j][3]));
        *(ushort4*)&xinb[((size_t)(b * 512 + n) << 12) + l] = hv;
      } else {
#pragma unroll
        for (int rr = 0; rr < 4; ++rr)
          zb16[(size_t)(mb + rr) * 512 + (n - 512)] = bf16rne(acc[i][j][rr]);
      }
    }
  }
}

// ---------------- gemm1: 128x128 tile, 1-term, fp32 out ---------------------
__global__ __launch_bounds__(256)
void gemm1_k(const unsigned short* __restrict__ Ag_, const unsigned short* __restrict__ Whi,
             float* __restrict__ o1)
{
  __shared__ char smem[32768];
  unsigned short* sA  = (unsigned short*)smem;
  unsigned short* sBh = (unsigned short*)(smem + 16384);
  const int tid = threadIdx.x;
  const int wave = tid >> 6, lane = tid & 63;

  const int nwg = gridDim.x;
  const int q = nwg >> 3, r = nwg & 7;
  const int xcd = blockIdx.x & 7, wi = blockIdx.x >> 3;
  const int logical = (xcd < r ? xcd * (q + 1) : r * (q + 1) + (xcd - r) * q) + wi;
  const int tm = logical >> 2, tn = logical & 3;
  const int m0 = tm << 7, n0 = tn << 7;

  const int wm = (wave & 1) << 6;
  const int wn = (wave >> 1) << 6;
  const int q16 = (lane >> 4) << 4;
  const int l15 = lane & 15;

  int srow[4], scol[4];
#pragma unroll
  for (int c = 0; c < 4; ++c) {
    int o = (wave << 12) + (c << 10) + (lane << 4);
    int row = o >> 7;
    srow[c] = row;
    scol[c] = (o & 127) ^ ((row & 7) << 4);
  }

  f32x4 acc[4][4];
#pragma unroll
  for (int i = 0; i < 4; ++i)
#pragma unroll
    for (int j = 0; j < 4; ++j) acc[i][j] = (f32x4){0.f, 0.f, 0.f, 0.f};

  for (int kt = 0; kt < 8; ++kt) {
    int kb = kt << 7;
    __syncthreads();
#pragma unroll
    for (int c = 0; c < 4; ++c) {
      size_t ga = (size_t)(m0 + srow[c]) * 1024 + kb + scol[c];
      size_t gb = (size_t)(n0 + srow[c]) * 1024 + kb + scol[c];
      int lo_ = (wave << 12) + (c << 10);
      gload16((const char*)Ag_ + ga, (char*)sA + lo_);
      gload16((const char*)Whi + gb, (char*)sBh + lo_);
    }
    __syncthreads();
#pragma unroll
    for (int ks = 0; ks < 2; ++ks) {
      short8 af[4], bh[4];
#pragma unroll
      for (int i = 0; i < 4; ++i) {
        int row = wm + (i << 4) + l15;
        int cb = ((ks << 6) + q16) ^ ((row & 7) << 4);
        af[i] = *(const short8*)((const char*)sA + (row << 7) + cb);
      }
#pragma unroll
      for (int j = 0; j < 4; ++j) {
        int row = wn + (j << 4) + l15;
        int cb = ((ks << 6) + q16) ^ ((row & 7) << 4);
        bh[j] = *(const short8*)((const char*)sBh + (row << 7) + cb);
      }
#pragma unroll
      for (int i = 0; i < 4; ++i)
#pragma unroll
        for (int j = 0; j < 4; ++j)
          acc[i][j] = __builtin_amdgcn_mfma_f32_16x16x32_bf16(af[i], bh[j], acc[i][j], 0, 0, 0);
    }
  }

  // stage C tile through LDS in two 64x128 halves; store coalesced float4
  float* sC = (float*)smem;           // 64 x 128 fp32 = 32 KB
  const int i_base = (lane >> 4) << 2;
#pragma unroll
  for (int half = 0; half < 2; ++half) {
    __syncthreads();
    if ((wave & 1) == half) {
#pragma unroll
      for (int j = 0; j < 4; ++j) {
        int nl = wn + (j << 4) + l15;
#pragma unroll
        for (int i = 0; i < 4; ++i) {
          int mloc = (i << 4) + i_base;
#pragma unroll
          for (int rr = 0; rr < 4; ++rr)
            sC[(mloc + rr) * 128 + nl] = acc[i][j][rr];
        }
      }
    }
    __syncthreads();
    int cx = (tid & 31) << 2;
    int r0 = tid >> 5;
#pragma unroll
    for (int it = 0; it < 8; ++it) {
      int row = r0 + (it << 3);
      *(float4*)&o1[(size_t)(m0 + (half << 6) + row) * 512 + n0 + cx] =
          *(float4*)&sC[row * 128 + cx];
    }
  }
}

// -------- depthwise 3x3 SAME (zero pad) + bias + silu, bf16 in, fp32 out ----
__global__ __launch_bounds__(256)
void conv_silu_k(const unsigned short* __restrict__ xin, const float* __restrict__ w,
                 const float* __restrict__ bias, float* __restrict__ xs)
{
  __shared__ float t[64][65];
  int plane = blockIdx.x;          // b*512 + d
  int d = plane & 511;
  int tid = threadIdx.x;
  const unsigned short* src = xin + (size_t)plane * 4096;
  int l0 = tid << 4, row = tid >> 2, c0 = (tid & 3) << 4;
  ushort8_t v0 = *(const ushort8_t*)&src[l0];
  ushort8_t v1 = *(const ushort8_t*)&src[l0 + 8];
#pragma unroll
  for (int j = 0; j < 8; ++j) {
    t[row][c0 + j]     = b2f(v0[j]);
    t[row][c0 + 8 + j] = b2f(v1[j]);
  }
  float wv[9];
#pragma unroll
  for (int j = 0; j < 9; j++) wv[j] = w[d * 9 + j];
  float bv = bias[d];
  __syncthreads();
  float* dst = xs + (size_t)plane * 4096;
#pragma unroll
  for (int i = 0; i < 16; i++) {
    int idx = tid + i * 256;
    int y = idx >> 6, x = idx & 63;
    float s = bv;
#pragma unroll
    for (int u = 0; u < 3; u++)
#pragma unroll
      for (int v = 0; v < 3; v++) {
        int yy = y + u - 1, xx = x + v - 1;
        if (yy >= 0 && yy < 64 && xx >= 0 && xx < 64)
          s = fmaf(wv[u * 3 + v], t[yy][xx], s);
      }
    dst[idx] = s * (1.f / (1.f + __expf(-s)));   // silu
  }
}

// ------- 3a: partial x_dbl GEMM: 8-way split over d; one pixel per thread ---
__global__ __launch_bounds__(256)
void xdbl_part_k(const float* __restrict__ xs, const float* __restrict__ xpw,
                 float* __restrict__ partial)
{
  __shared__ float sw[34 * 64];    // xpw chunk, [k][dd]
  int tid = threadIdx.x;
  int p  = blockIdx.x * 256 + tid;   // pixel 0..16383 (b*4096+l)
  int d0 = blockIdx.y * 64;
  int b = p >> 12, l = p & 4095;
  for (int i = tid; i < 34 * 64; i += 256) {
    int k = i >> 6, dd = i & 63;
    sw[i] = xpw[k * 512 + d0 + dd];
  }
  __syncthreads();
  float acc[34];
#pragma unroll
  for (int k = 0; k < 34; k++) acc[k] = 0.f;
  const float* xp = xs + (size_t)(b * 512 + d0) * 4096 + l;
#pragma unroll 4
  for (int dd = 0; dd < 64; dd++) {
    float v = xp[(size_t)dd * 4096];
#pragma unroll
    for (int k = 0; k < 34; k++) acc[k] = fmaf(sw[k * 64 + dd], v, acc[k]);
  }
  float* op = partial + (size_t)blockIdx.y * 34 * 16384 + p;
#pragma unroll
  for (int k = 0; k < 34; k++) op[(size_t)k * 16384] = acc[k];
}

// ------- 3b: reduce 8 partials -> xdbl_r[34][16384] -------------------------
__global__ __launch_bounds__(256)
void xdbl_reduce_k(const float* __restrict__ partial, float* __restrict__ xdbl_r)
{
  int gid = blockIdx.x * 256 + threadIdx.x;   // 0 .. 34*16384-1
  float s = 0.f;
#pragma unroll
  for (int sp = 0; sp < 8; sp++) s += partial[(size_t)sp * 34 * 16384 + gid];
  xdbl_r[gid] = s;
}

// ------- 3c: dts -> softplus -> delta only ----------------------------------
__global__ __launch_bounds__(256)
void delta_k(const float* __restrict__ xdbl_r, const float* __restrict__ dtw,
             const float* __restrict__ dtb, float* __restrict__ del)
{
  __shared__ float sm[32][256];    // dt-rank rows
  int tid = threadIdx.x;
  int l0 = blockIdx.x * 256;       // l tile within batch
  int d0 = blockIdx.y * 64;        // d chunk
  int b  = blockIdx.z;
  int p0 = b * 4096 + l0;
#pragma unroll
  for (int k = 0; k < 32; k++) sm[k][tid] = xdbl_r[k * 16384 + p0 + tid];
  __syncthreads();
#pragma unroll 2
  for (int dd = 0; dd < 64; dd++) {
    int d = d0 + dd;
    float s = dtb[d];
#pragma unroll
    for (int r = 0; r < 32; r++) s = fmaf(dtw[d * 32 + r], sm[r][tid], s);
    float delta = fmaxf(s, 0.f) + __logf(1.f + __expf(-fabsf(s)));  // softplus
    del[((size_t)(b * 512 + d) << 12) + l0 + tid] = delta;
  }
}

// ---- fused: a/bb on-the-fly + thread-serial(16)+wave scan + dilated convs --
__global__ __launch_bounds__(256)
void scan_sfconv_k(const float* __restrict__ del, const float* __restrict__ Bsr,
                   const float* __restrict__ xs, const float* __restrict__ A_logs,
                   const float* __restrict__ k1, const float* __restrict__ k2,
                   const float* __restrict__ k3, const float* __restrict__ alpha,
                   const float* __restrict__ Cs, const float* __restrict__ Ds,
                   unsigned short* __restrict__ ypre)
{
  __shared__ float t[64][65];      // h grid, conv source
  __shared__ float segA[4], segH[4];
  int plane = blockIdx.x;
  int d = plane & 511;
  int b = plane >> 9;
  int tid = threadIdx.x;
  int wave = tid >> 6, lane = tid & 63;
  size_t base = (size_t)plane * 4096;
  float Ad = -__expf(A_logs[d]);

  const int l0 = tid << 4;
  float a_reg[16], b_reg[16], x_reg[16];
#pragma unroll
  for (int k = 0; k < 4; ++k) {
    float4 dv4 = *(const float4*)&del[base + l0 + k * 4];
    float4 bs4 = *(const float4*)&Bsr[(b << 12) + l0 + k * 4];
    float4 xs4 = *(const float4*)&xs[base + l0 + k * 4];
    float dv[4] = {dv4.x, dv4.y, dv4.z, dv4.w};
    float bs[4] = {bs4.x, bs4.y, bs4.z, bs4.w};
    float xv[4] = {xs4.x, xs4.y, xs4.z, xs4.w};
#pragma unroll
    for (int j = 0; j < 4; ++j) {
      a_reg[k * 4 + j] = __expf(dv[j] * Ad);
      b_reg[k * 4 + j] = dv[j] * bs[j] * xv[j];
      x_reg[k * 4 + j] = xv[j];
    }
  }

  float A_th = a_reg[0], H_th = b_reg[0];
#pragma unroll
  for (int j = 1; j < 16; ++j) {
    H_th = fmaf(a_reg[j], H_th, b_reg[j]);
    A_th *= a_reg[j];
  }

#pragma unroll
  for (int off = 1; off < 64; off <<= 1) {
    float Ap = __shfl_up(A_th, off);
    float Hp = __shfl_up(H_th, off);
    if (lane >= off) { H_th = fmaf(A_th, Hp, H_th); A_th *= Ap; }
  }
  float eA = __shfl_up(A_th, 1);
  float eH = __shfl_up(H_th, 1);
  if (lane == 0) { eA = 1.f; eH = 0.f; }
  if (lane == 63) { segA[wave] = A_th; segH[wave] = H_th; }
  __syncthreads();

  float cy1 = segH[0];
  float cy2 = fmaf(segA[1], cy1, segH[1]);
  float cy3 = fmaf(segA[2], cy2, segH[2]);
  float myc = (wave == 1) ? cy1 : (wave == 2) ? cy2 : (wave == 3) ? cy3 : 0.f;
  float h = fmaf(eA, myc, eH);     // h entering this thread's segment

  int row = tid >> 2, c0 = (tid & 3) << 4;
#pragma unroll
  for (int j = 0; j < 16; ++j) {
    h = fmaf(a_reg[j], h, b_reg[j]);
    t[row][c0 + j] = h;
  }
  __syncthreads();

  float wv[3][9];
  float a0 = alpha[0], a1 = alpha[1], a2 = alpha[2];
#pragma unroll
  for (int j = 0; j < 9; j++) {
    wv[0][j] = a0 * k1[d * 9 + j];
    wv[1][j] = a1 * k2[d * 9 + j];
    wv[2][j] = a2 * k3[d * 9 + j];
  }
  float Dv = Ds[d];
  float cs_reg[16];
#pragma unroll
  for (int k = 0; k < 4; ++k) {
    float4 c4 = *(const float4*)&Cs[(b << 12) + l0 + k * 4];
    cs_reg[k * 4 + 0] = c4.x; cs_reg[k * 4 + 1] = c4.y;
    cs_reg[k * 4 + 2] = c4.z; cs_reg[k * 4 + 3] = c4.w;
  }
  unsigned short ov[16];
  const int y = row;               // constant per thread
#pragma unroll
  for (int j = 0; j < 16; j++) {
    int x = c0 + j;
    float s = 0.f;
#pragma unroll
    for (int dil = 1; dil <= 3; dil++)
#pragma unroll
      for (int uu = 0; uu < 3; uu++)
#pragma unroll
        for (int vv = 0; vv < 3; vv++) {
          int yy = y + (uu - 1) * dil; yy = yy < 0 ? 0 : (yy > 63 ? 63 : yy);
          int xx = x + (vv - 1) * dil; xx = xx < 0 ? 0 : (xx > 63 ? 63 : xx);
          s = fmaf(wv[dil - 1][uu * 3 + vv], t[yy][xx], s);
        }
    ov[j] = bf16rne(fmaf(s, cs_reg[j], x_reg[j] * Dv));
  }
  ushort8_t o0, o1;
#pragma unroll
  for (int j = 0; j < 8; ++j) { o0[j] = ov[j]; o1[j] = ov[8 + j]; }
  *(ushort8_t*)&ypre[base + l0]     = o0;
  *(ushort8_t*)&ypre[base + l0 + 8] = o1;
}

// ---------------- bf16 transpose (B,D,L) -> (B,L,D) --------------------------
__global__ __launch_bounds__(256)
void transpose_bf16_k(const unsigned short* __restrict__ src,
                      unsigned short* __restrict__ dst)
{
  __shared__ unsigned short t[64][72];   // [l][d], pad 72
  int l0 = blockIdx.x * 64;
  int d0 = blockIdx.y * 64;
  int b  = blockIdx.z;
  int tid = threadIdx.x;
  int dl = tid & 63, lg0 = tid >> 6;
#pragma unroll
  for (int i = 0; i < 2; ++i) {
    int lg = lg0 + i * 4;                // l-chunk of 8
    ushort8_t v = *(const ushort8_t*)&src[(size_t)(b * 512 + d0 + dl) * 4096 + l0 + lg * 8];
#pragma unroll
    for (int j = 0; j < 8; ++j) t[lg * 8 + j][dl] = v[j];
  }
  __syncthreads();
  int pl = tid >> 2, c0 = (tid & 3) << 4;
  ushort8_t a = *(const ushort8_t*)&t[pl][c0];
  ushort8_t bb = *(const ushort8_t*)&t[pl][c0 + 8];
  size_t o = (size_t)(b * 4096 + l0 + pl) * 512 + d0 + c0;
  *(ushort8_t*)&dst[o] = a;
  *(ushort8_t*)&dst[o + 8] = bb;
}

// -------- LayerNorm over D + silu(z) gate, bf16 in/out ----------------------
__global__ __launch_bounds__(256)
void ln_silu_split_k(const unsigned short* __restrict__ y,
                     const unsigned short* __restrict__ z,
                     const float* __restrict__ lw, const float* __restrict__ lb,
                     unsigned short* __restrict__ hi)
{
  int wid = threadIdx.x >> 6, lane = threadIdx.x & 63;
  int pix = blockIdx.x * 4 + wid;            // 0..16383
  const unsigned short* yp = y + (size_t)pix * 512;
  const unsigned short* zp = z + (size_t)pix * 512;
  ushort8_t yv8 = *(const ushort8_t*)&yp[lane * 8];
  float vv[8];
#pragma unroll
  for (int j = 0; j < 8; j++) vv[j] = b2f(yv8[j]);
  float sum = 0.f;
#pragma unroll
  for (int j = 0; j < 8; j++) sum += vv[j];
#pragma unroll
  for (int off = 1; off < 64; off <<= 1) sum += __shfl_xor(sum, off);
  float mu = sum * (1.f / 512.f);
  float q = 0.f;
#pragma unroll
  for (int j = 0; j < 8; j++) { float dd = vv[j] - mu; q += dd * dd; }
#pragma unroll
  for (int off = 1; off < 64; off <<= 1) q += __shfl_xor(q, off);
  float rstd = rsqrtf(q * (1.f / 512.f) + 1e-5f);
  ushort8_t zv8 = *(const ushort8_t*)&zp[lane * 8];
  unsigned short oh[8];
#pragma unroll
  for (int j = 0; j < 8; j++) {
    int dch = lane * 8 + j;
    float val = (vv[j] - mu) * rstd * lw[dch] + lb[dch];
    float zv = b2f(zv8[j]);
    float ov = val * (zv * (1.f / (1.f + __expf(-zv))));
    oh[j] = bf16rne(ov);
  }
  size_t o = (size_t)pix * 512 + lane * 8;
  *(ushort4*)&hi[o]     = make_ushort4(oh[0], oh[1], oh[2], oh[3]);
  *(ushort4*)&hi[o + 4] = make_ushort4(oh[4], oh[5], oh[6], oh[7]);
}

extern "C" void kernel_launch(void* const* d_in, const int* in_sizes, int n_in,
                              void* d_out, int out_size, void* d_ws, size_t ws_size,
                              hipStream_t stream)
{
  const float* x    = (const float*)d_in[0];
  const float* win  = (const float*)d_in[1];
  const float* cw   = (const float*)d_in[2];
  const float* cb   = (const float*)d_in[3];
  const float* xpw  = (const float*)d_in[4];
  const float* dtw  = (const float*)d_in[5];
  const float* dtb  = (const float*)d_in[6];
  const float* alog = (const float*)d_in[7];
  const float* Dsv  = (const float*)d_in[8];
  const float* k1   = (const float*)d_in[9];
  const float* k2   = (const float*)d_in[10];
  const float* k3   = (const float*)d_in[11];
  const float* alp  = (const float*)d_in[12];
  const float* lw   = (const float*)d_in[13];
  const float* lb   = (const float*)d_in[14];
  const float* wout = (const float*)d_in[15];
  float* out = (float*)d_out;

  const size_t NP = (size_t)4 * 512 * 4096;   // 8,388,608 elems per (B,D,L) buffer
  float* ws = (float*)d_ws;
  float* xs     = ws;                 // Whi/Wlo -> xs fp32 -> y_t bf16 -> Ohi
  float* zbuf   = ws + NP;            // z bf16 (1st half) | ypre bf16 (2nd half)
  float* w4     = ws + 2 * NP;        // Ahi -> delta -> Yhi
  float* xdbl_r = ws + 3 * NP;        // 34 x 16384

  unsigned short* Ahi  = (unsigned short*)w4;        // 16384x512 bf16
  unsigned short* Whi  = (unsigned short*)xs;        // 1024x512 bf16
  unsigned short* Wlo  = Whi + (size_t)1024 * 512;
  unsigned short* xinb = (unsigned short*)d_out;     // xin bf16 (d_out scratch)
  unsigned short* zb16 = (unsigned short*)zbuf;              // 16384x512 bf16
  unsigned short* yp16 = zb16 + (size_t)16384 * 512;         // ypre bf16
  unsigned short* yt16 = (unsigned short*)xs;        // y_t bf16 (xs dead)
  unsigned short* Yhi  = (unsigned short*)w4;        // after delta consumed
  unsigned short* Ohi  = (unsigned short*)xs;        // after y_t consumed
  float* xsf = xs;                                   // xs fp32 view

  cvt_hi_k<<<8192, 256, 0, stream>>>(x, Ahi, 2097152);                      // x -> bf16
  split_k<<<512, 256, 0, stream>>>(win, Whi, Wlo, 131072);                  // win -> hi/lo
  gemm0_k<<<512, 256, 0, stream>>>(Ahi, Whi, Wlo, xinb, zb16);              // xin, z (bf16)
  conv_silu_k<<<2048, 256, 0, stream>>>(xinb, cw, cb, xsf);                 // xs fp32
  xdbl_part_k<<<dim3(64, 8), 256, 0, stream>>>(xsf, xpw, out);              // partial->d_out
  xdbl_reduce_k<<<2176, 256, 0, stream>>>(out, xdbl_r);                     // xdbl_r
  delta_k<<<dim3(16, 8, 4), 256, 0, stream>>>(xdbl_r, dtw, dtb, w4);        // delta->w4
  scan_sfconv_k<<<2048, 256, 0, stream>>>(w4, xdbl_r + 32 * 16384, xsf, alog,
                                          k1, k2, k3, alp,
                                          xdbl_r + 33 * 16384, Dsv, yp16);  // ypre bf16
  transpose_bf16_k<<<dim3(64, 8, 4), 256, 0, stream>>>(yp16, yt16);         // y_t bf16
  ln_silu_split_k<<<4096, 256, 0, stream>>>(yt16, zb16, lw, lb, Yhi);       // y -> bf16
  cvt_hi_k<<<256, 256, 0, stream>>>(wout, Ohi, 65536);                      // wout -> bf16
  gemm1_k<<<512, 256, 0, stream>>>(Yhi, Ohi, out);                          // final 1-term
}

// Round 16
// 177.407 us; speedup vs baseline: 1.1125x; 1.0022x over previous
//
#include <hip/hip_runtime.h>
#include <cstddef>

// B=4, L=4096 (=64x64), d_model=512, d_inner=512, dt_rank=32, d_state=1
// GEMMs: 2-phase double-buffered pipeline (stage t+1 BEFORE compute t; one
// __syncthreads per step drains loads that overlapped compute). BK=32,
// 64B-row XOR swizzle (col ^= (row&3)<<4), 128x128 tiles.
// gemm0: xin-half 2-term bf16, z-half 1-term; 48 KB LDS (3 blk/CU).
// gemm1: 1-term; 32 KB LDS (5 blk/CU).
// bf16 intermediates: xin, z, ypre/y_t. scan: thread-serial(16)+wave-scan.

typedef __attribute__((ext_vector_type(8))) short short8;
typedef __attribute__((ext_vector_type(8))) unsigned short ushort8_t;
typedef __attribute__((ext_vector_type(4))) float f32x4;

__device__ __forceinline__ void gload16(const void* g, void* l) {
  __builtin_amdgcn_global_load_lds(
      (const __attribute__((address_space(1))) void*)g,
      (__attribute__((address_space(3))) void*)l, 16, 0, 0);
}

__device__ __forceinline__ void bf16split(float v, unsigned short& h, unsigned short& l) {
  unsigned u = __float_as_uint(v);
  unsigned uh = (u + 0x7fffu + ((u >> 16) & 1u)) & 0xffff0000u;
  h = (unsigned short)(uh >> 16);
  float rem = v - __uint_as_float(uh);
  unsigned ur = __float_as_uint(rem);
  l = (unsigned short)((ur + 0x7fffu + ((ur >> 16) & 1u)) >> 16);
}

__device__ __forceinline__ unsigned short bf16rne(float v) {
  unsigned u = __float_as_uint(v);
  return (unsigned short)((u + 0x7fffu + ((u >> 16) & 1u)) >> 16);
}

__device__ __forceinline__ float b2f(unsigned short u) {
  return __uint_as_float((unsigned)u << 16);
}

// ------- prep: x -> bf16 (blocks 0..8191); win -> hi/lo split (8192..8703) --
__global__ __launch_bounds__(256)
void prep_k(const float* __restrict__ x, const float* __restrict__ win,
            unsigned short* __restrict__ Ahi,
            unsigned short* __restrict__ Whi, unsigned short* __restrict__ Wlo)
{
  int bid = blockIdx.x;
  if (bid < 8192) {
    int i = bid * 256 + threadIdx.x;            // < 2097152
    float4 v = ((const float4*)x)[i];
    ((ushort4*)Ahi)[i] = make_ushort4(bf16rne(v.x), bf16rne(v.y), bf16rne(v.z), bf16rne(v.w));
  } else {
    int i = (bid - 8192) * 256 + threadIdx.x;   // < 131072
    float4 v = ((const float4*)win)[i];
    float vv[4] = {v.x, v.y, v.z, v.w};
    unsigned short h[4], l[4];
#pragma unroll
    for (int j = 0; j < 4; ++j) bf16split(vv[j], h[j], l[j]);
    ((ushort4*)Whi)[i] = make_ushort4(h[0], h[1], h[2], h[3]);
    ((ushort4*)Wlo)[i] = make_ushort4(l[0], l[1], l[2], l[3]);
  }
}

// ---------------- fp32 -> bf16 RNE ------------------------------------------
__global__ __launch_bounds__(256)
void cvt_hi_k(const float* __restrict__ in, unsigned short* __restrict__ hi, int n4)
{
  int i = blockIdx.x * 256 + threadIdx.x;
  if (i >= n4) return;
  float4 v = ((const float4*)in)[i];
  ((ushort4*)hi)[i] = make_ushort4(bf16rne(v.x), bf16rne(v.y), bf16rne(v.z), bf16rne(v.w));
}

// ---------------- gemm0: 128x128, BK=32, 2-phase dbuf, dual bf16 out --------
// 4 waves 2m x 2n. xin-half (n0<512): 2-term; z-half: 1-term.
__global__ __launch_bounds__(256)
void gemm0_k(const unsigned short* __restrict__ Ahi, const unsigned short* __restrict__ Whi,
             const unsigned short* __restrict__ Wlo,
             unsigned short* __restrict__ xinb, unsigned short* __restrict__ zb16)
{
  __shared__ char smem[49152];     // 2 bufs x {A 8K | Bh 8K | Bl 8K}
  const int tid = threadIdx.x;
  const int wave = tid >> 6, lane = tid & 63;

  const int nwg = gridDim.x;       // 1024
  const int q = nwg >> 3, r = nwg & 7;
  const int xcd = blockIdx.x & 7, wi = blockIdx.x >> 3;
  const int logical = (xcd < r ? xcd * (q + 1) : r * (q + 1) + (xcd - r) * q) + wi;
  const int tm = logical >> 3, tn = logical & 7;
  const int m0 = tm << 7, n0 = tn << 7;
  const bool two = (n0 < 512);

  const int wm = (wave & 1) << 6;
  const int wn = (wave >> 1) << 6;
  const int q16 = (lane >> 4) << 4;
  const int l15 = lane & 15;

  // staging descriptors: panel 8 KB, 2 chunks/lane, rows of 64B
  int srow[2], scol[2];
#pragma unroll
  for (int c = 0; c < 2; ++c) {
    int o = (wave << 11) + (c << 10) + (lane << 4);
    int row = o >> 6;
    srow[c] = row;
    scol[c] = (o & 63) ^ ((row & 3) << 4);
  }

  f32x4 acc[4][4];
#pragma unroll
  for (int i = 0; i < 4; ++i)
#pragma unroll
    for (int j = 0; j < 4; ++j) acc[i][j] = (f32x4){0.f, 0.f, 0.f, 0.f};

  const char* Ag = (const char*)Ahi;
  const char* Bh = (const char*)Whi;
  const char* Bl = (const char*)Wlo;

#define G0_STAGE(buf, kt)                                                     \
  {                                                                           \
    char* base_ = smem + (buf) * 24576;                                       \
    int kb_ = (kt) << 6;                                                      \
    _Pragma("unroll")                                                         \
    for (int c = 0; c < 2; ++c) {                                             \
      int lo_ = (wave << 11) + (c << 10);                                     \
      gload16(Ag + (size_t)(m0 + srow[c]) * 1024 + kb_ + scol[c], base_ + lo_);       \
      gload16(Bh + (size_t)(n0 + srow[c]) * 1024 + kb_ + scol[c], base_ + 8192 + lo_);\
      if (two)                                                                \
        gload16(Bl + (size_t)(n0 + srow[c]) * 1024 + kb_ + scol[c], base_ + 16384 + lo_);\
    }                                                                         \
  }

  G0_STAGE(0, 0);
  __syncthreads();
  for (int kt = 0; kt < 16; ++kt) {
    int cur = kt & 1;
    if (kt < 15) G0_STAGE(cur ^ 1, kt + 1);
    const char* bp = smem + cur * 24576;
    short8 af[4], bh[4], bl[4];
#pragma unroll
    for (int i = 0; i < 4; ++i) {
      int row = wm + (i << 4) + l15;
      int cb = q16 ^ ((row & 3) << 4);
      af[i] = *(const short8*)(bp + (row << 6) + cb);
    }
#pragma unroll
    for (int j = 0; j < 4; ++j) {
      int row = wn + (j << 4) + l15;
      int cb = q16 ^ ((row & 3) << 4);
      bh[j] = *(const short8*)(bp + 8192 + (row << 6) + cb);
      if (two) bl[j] = *(const short8*)(bp + 16384 + (row << 6) + cb);
    }
#pragma unroll
    for (int i = 0; i < 4; ++i)
#pragma unroll
      for (int j = 0; j < 4; ++j) {
        acc[i][j] = __builtin_amdgcn_mfma_f32_16x16x32_bf16(af[i], bh[j], acc[i][j], 0, 0, 0);
        if (two)
          acc[i][j] = __builtin_amdgcn_mfma_f32_16x16x32_bf16(af[i], bl[j], acc[i][j], 0, 0, 0);
      }
    __syncthreads();
  }
#undef G0_STAGE

  const int mb_base = m0 + wm + ((lane >> 4) << 2);
#pragma unroll
  for (int j = 0; j < 4; ++j) {
    int n = n0 + wn + (j << 4) + l15;
#pragma unroll
    for (int i = 0; i < 4; ++i) {
      int mb = mb_base + (i << 4);
      if (n < 512) {
        int b = mb >> 12, l = mb & 4095;
        ushort4 hv = make_ushort4(bf16rne(acc[i][j][0]), bf16rne(acc[i][j][1]),
                                  bf16rne(acc[i][j][2]), bf16rne(acc[i][j][3]));
        *(ushort4*)&xinb[((size_t)(b * 512 + n) << 12) + l] = hv;
      } else {
#pragma unroll
        for (int rr = 0; rr < 4; ++rr)
          zb16[(size_t)(mb + rr) * 512 + (n - 512)] = bf16rne(acc[i][j][rr]);
      }
    }
  }
}

// ---------------- gemm1: 128x128, BK=32, 2-phase dbuf, 1-term, fp32 out -----
__global__ __launch_bounds__(256)
void gemm1_k(const unsigned short* __restrict__ Ag_, const unsigned short* __restrict__ Whi,
             float* __restrict__ o1)
{
  __shared__ char smem[32768];     // 2 bufs x {A 8K | B 8K}
  const int tid = threadIdx.x;
  const int wave = tid >> 6, lane = tid & 63;

  const int nwg = gridDim.x;       // 512
  const int q = nwg >> 3, r = nwg & 7;
  const int xcd = blockIdx.x & 7, wi = blockIdx.x >> 3;
  const int logical = (xcd < r ? xcd * (q + 1) : r * (q + 1) + (xcd - r) * q) + wi;
  const int tm = logical >> 2, tn = logical & 3;
  const int m0 = tm << 7, n0 = tn << 7;

  const int wm = (wave & 1) << 6;
  const int wn = (wave >> 1) << 6;
  const int q16 = (lane >> 4) << 4;
  const int l15 = lane & 15;

  int srow[2], scol[2];
#pragma unroll
  for (int c = 0; c < 2; ++c) {
    int o = (wave << 11) + (c << 10) + (lane << 4);
    int row = o >> 6;
    srow[c] = row;
    scol[c] = (o & 63) ^ ((row & 3) << 4);
  }

  f32x4 acc[4][4];
#pragma unroll
  for (int i = 0; i < 4; ++i)
#pragma unroll
    for (int j = 0; j < 4; ++j) acc[i][j] = (f32x4){0.f, 0.f, 0.f, 0.f};

  const char* Ag = (const char*)Ag_;
  const char* Bg = (const char*)Whi;

#define G1_STAGE(buf, kt)                                                     \
  {                                                                           \
    char* base_ = smem + (buf) * 16384;                                       \
    int kb_ = (kt) << 6;                                                      \
    _Pragma("unroll")                                                         \
    for (int c = 0; c < 2; ++c) {                                             \
      int lo_ = (wave << 11) + (c << 10);                                     \
      gload16(Ag + (size_t)(m0 + srow[c]) * 1024 + kb_ + scol[c], base_ + lo_);       \
      gload16(Bg + (size_t)(n0 + srow[c]) * 1024 + kb_ + scol[c], base_ + 8192 + lo_);\
    }                                                                         \
  }

  G1_STAGE(0, 0);
  __syncthreads();
  for (int kt = 0; kt < 16; ++kt) {
    int cur = kt & 1;
    if (kt < 15) G1_STAGE(cur ^ 1, kt + 1);
    const char* bp = smem + cur * 16384;
    short8 af[4], bh[4];
#pragma unroll
    for (int i = 0; i < 4; ++i) {
      int row = wm + (i << 4) + l15;
      int cb = q16 ^ ((row & 3) << 4);
      af[i] = *(const short8*)(bp + (row << 6) + cb);
    }
#pragma unroll
    for (int j = 0; j < 4; ++j) {
      int row = wn + (j << 4) + l15;
      int cb = q16 ^ ((row & 3) << 4);
      bh[j] = *(const short8*)(bp + 8192 + (row << 6) + cb);
    }
#pragma unroll
    for (int i = 0; i < 4; ++i)
#pragma unroll
      for (int j = 0; j < 4; ++j)
        acc[i][j] = __builtin_amdgcn_mfma_f32_16x16x32_bf16(af[i], bh[j], acc[i][j], 0, 0, 0);
    __syncthreads();
  }
#undef G1_STAGE

  // stage C tile through LDS in two 64x128 halves; store coalesced float4
  float* sC = (float*)smem;           // 64 x 128 fp32 = 32 KB
  const int i_base = (lane >> 4) << 2;
#pragma unroll
  for (int half = 0; half < 2; ++half) {
    __syncthreads();
    if ((wave & 1) == half) {
#pragma unroll
      for (int j = 0; j < 4; ++j) {
        int nl = wn + (j << 4) + l15;
#pragma unroll
        for (int i = 0; i < 4; ++i) {
          int mloc = (i << 4) + i_base;
#pragma unroll
          for (int rr = 0; rr < 4; ++rr)
            sC[(mloc + rr) * 128 + nl] = acc[i][j][rr];
        }
      }
    }
    __syncthreads();
    int cx = (tid & 31) << 2;
    int r0 = tid >> 5;
#pragma unroll
    for (int it = 0; it < 8; ++it) {
      int row = r0 + (it << 3);
      *(float4*)&o1[(size_t)(m0 + (half << 6) + row) * 512 + n0 + cx] =
          *(float4*)&sC[row * 128 + cx];
    }
  }
}

// -------- depthwise 3x3 SAME (zero pad) + bias + silu, bf16 in, fp32 out ----
__global__ __launch_bounds__(256)
void conv_silu_k(const unsigned short* __restrict__ xin, const float* __restrict__ w,
                 const float* __restrict__ bias, float* __restrict__ xs)
{
  __shared__ float t[64][65];
  int plane = blockIdx.x;          // b*512 + d
  int d = plane & 511;
  int tid = threadIdx.x;
  const unsigned short* src = xin + (size_t)plane * 4096;
  int l0 = tid << 4, row = tid >> 2, c0 = (tid & 3) << 4;
  ushort8_t v0 = *(const ushort8_t*)&src[l0];
  ushort8_t v1 = *(const ushort8_t*)&src[l0 + 8];
#pragma unroll
  for (int j = 0; j < 8; ++j) {
    t[row][c0 + j]     = b2f(v0[j]);
    t[row][c0 + 8 + j] = b2f(v1[j]);
  }
  float wv[9];
#pragma unroll
  for (int j = 0; j < 9; j++) wv[j] = w[d * 9 + j];
  float bv = bias[d];
  __syncthreads();
  float* dst = xs + (size_t)plane * 4096;
#pragma unroll
  for (int i = 0; i < 16; i++) {
    int idx = tid + i * 256;
    int y = idx >> 6, x = idx & 63;
    float s = bv;
#pragma unroll
    for (int u = 0; u < 3; u++)
#pragma unroll
      for (int v = 0; v < 3; v++) {
        int yy = y + u - 1, xx = x + v - 1;
        if (yy >= 0 && yy < 64 && xx >= 0 && xx < 64)
          s = fmaf(wv[u * 3 + v], t[yy][xx], s);
      }
    dst[idx] = s * (1.f / (1.f + __expf(-s)));   // silu
  }
}

// ------- 3a: partial x_dbl GEMM: 8-way split over d; one pixel per thread ---
__global__ __launch_bounds__(256)
void xdbl_part_k(const float* __restrict__ xs, const float* __restrict__ xpw,
                 float* __restrict__ partial)
{
  __shared__ float sw[34 * 64];    // xpw chunk, [k][dd]
  int tid = threadIdx.x;
  int p  = blockIdx.x * 256 + tid;   // pixel 0..16383 (b*4096+l)
  int d0 = blockIdx.y * 64;
  int b = p >> 12, l = p & 4095;
  for (int i = tid; i < 34 * 64; i += 256) {
    int k = i >> 6, dd = i & 63;
    sw[i] = xpw[k * 512 + d0 + dd];
  }
  __syncthreads();
  float acc[34];
#pragma unroll
  for (int k = 0; k < 34; k++) acc[k] = 0.f;
  const float* xp = xs + (size_t)(b * 512 + d0) * 4096 + l;
#pragma unroll 4
  for (int dd = 0; dd < 64; dd++) {
    float v = xp[(size_t)dd * 4096];
#pragma unroll
    for (int k = 0; k < 34; k++) acc[k] = fmaf(sw[k * 64 + dd], v, acc[k]);
  }
  float* op = partial + (size_t)blockIdx.y * 34 * 16384 + p;
#pragma unroll
  for (int k = 0; k < 34; k++) op[(size_t)k * 16384] = acc[k];
}

// ------- 3b: reduce 8 partials -> xdbl_r[34][16384] -------------------------
__global__ __launch_bounds__(256)
void xdbl_reduce_k(const float* __restrict__ partial, float* __restrict__ xdbl_r)
{
  int gid = blockIdx.x * 256 + threadIdx.x;   // 0 .. 34*16384-1
  float s = 0.f;
#pragma unroll
  for (int sp = 0; sp < 8; sp++) s += partial[(size_t)sp * 34 * 16384 + gid];
  xdbl_r[gid] = s;
}

// ------- 3c: dts -> softplus -> delta only ----------------------------------
__global__ __launch_bounds__(256)
void delta_k(const float* __restrict__ xdbl_r, const float* __restrict__ dtw,
             const float* __restrict__ dtb, float* __restrict__ del)
{
  __shared__ float sm[32][256];    // dt-rank rows
  int tid = threadIdx.x;
  int l0 = blockIdx.x * 256;       // l tile within batch
  int d0 = blockIdx.y * 64;        // d chunk
  int b  = blockIdx.z;
  int p0 = b * 4096 + l0;
#pragma unroll
  for (int k = 0; k < 32; k++) sm[k][tid] = xdbl_r[k * 16384 + p0 + tid];
  __syncthreads();
#pragma unroll 2
  for (int dd = 0; dd < 64; dd++) {
    int d = d0 + dd;
    float s = dtb[d];
#pragma unroll
    for (int r = 0; r < 32; r++) s = fmaf(dtw[d * 32 + r], sm[r][tid], s);
    float delta = fmaxf(s, 0.f) + __logf(1.f + __expf(-fabsf(s)));  // softplus
    del[((size_t)(b * 512 + d) << 12) + l0 + tid] = delta;
  }
}

// ---- fused: a/bb on-the-fly + thread-serial(16)+wave scan + dilated convs --
__global__ __launch_bounds__(256)
void scan_sfconv_k(const float* __restrict__ del, const float* __restrict__ Bsr,
                   const float* __restrict__ xs, const float* __restrict__ A_logs,
                   const float* __restrict__ k1, const float* __restrict__ k2,
                   const float* __restrict__ k3, const float* __restrict__ alpha,
                   const float* __restrict__ Cs, const float* __restrict__ Ds,
                   unsigned short* __restrict__ ypre)
{
  __shared__ float t[64][65];      // h grid, conv source
  __shared__ float segA[4], segH[4];
  int plane = blockIdx.x;
  int d = plane & 511;
  int b = plane >> 9;
  int tid = threadIdx.x;
  int wave = tid >> 6, lane = tid & 63;
  size_t base = (size_t)plane * 4096;
  float Ad = -__expf(A_logs[d]);

  const int l0 = tid << 4;
  float a_reg[16], b_reg[16], x_reg[16];
#pragma unroll
  for (int k = 0; k < 4; ++k) {
    float4 dv4 = *(const float4*)&del[base + l0 + k * 4];
    float4 bs4 = *(const float4*)&Bsr[(b << 12) + l0 + k * 4];
    float4 xs4 = *(const float4*)&xs[base + l0 + k * 4];
    float dv[4] = {dv4.x, dv4.y, dv4.z, dv4.w};
    float bs[4] = {bs4.x, bs4.y, bs4.z, bs4.w};
    float xv[4] = {xs4.x, xs4.y, xs4.z, xs4.w};
#pragma unroll
    for (int j = 0; j < 4; ++j) {
      a_reg[k * 4 + j] = __expf(dv[j] * Ad);
      b_reg[k * 4 + j] = dv[j] * bs[j] * xv[j];
      x_reg[k * 4 + j] = xv[j];
    }
  }

  float A_th = a_reg[0], H_th = b_reg[0];
#pragma unroll
  for (int j = 1; j < 16; ++j) {
    H_th = fmaf(a_reg[j], H_th, b_reg[j]);
    A_th *= a_reg[j];
  }

#pragma unroll
  for (int off = 1; off < 64; off <<= 1) {
    float Ap = __shfl_up(A_th, off);
    float Hp = __shfl_up(H_th, off);
    if (lane >= off) { H_th = fmaf(A_th, Hp, H_th); A_th *= Ap; }
  }
  float eA = __shfl_up(A_th, 1);
  float eH = __shfl_up(H_th, 1);
  if (lane == 0) { eA = 1.f; eH = 0.f; }
  if (lane == 63) { segA[wave] = A_th; segH[wave] = H_th; }
  __syncthreads();

  float cy1 = segH[0];
  float cy2 = fmaf(segA[1], cy1, segH[1]);
  float cy3 = fmaf(segA[2], cy2, segH[2]);
  float myc = (wave == 1) ? cy1 : (wave == 2) ? cy2 : (wave == 3) ? cy3 : 0.f;
  float h = fmaf(eA, myc, eH);     // h entering this thread's segment

  int row = tid >> 2, c0 = (tid & 3) << 4;
#pragma unroll
  for (int j = 0; j < 16; ++j) {
    h = fmaf(a_reg[j], h, b_reg[j]);
    t[row][c0 + j] = h;
  }
  __syncthreads();

  float wv[3][9];
  float a0 = alpha[0], a1 = alpha[1], a2 = alpha[2];
#pragma unroll
  for (int j = 0; j < 9; j++) {
    wv[0][j] = a0 * k1[d * 9 + j];
    wv[1][j] = a1 * k2[d * 9 + j];
    wv[2][j] = a2 * k3[d * 9 + j];
  }
  float Dv = Ds[d];
  float cs_reg[16];
#pragma unroll
  for (int k = 0; k < 4; ++k) {
    float4 c4 = *(const float4*)&Cs[(b << 12) + l0 + k * 4];
    cs_reg[k * 4 + 0] = c4.x; cs_reg[k * 4 + 1] = c4.y;
    cs_reg[k * 4 + 2] = c4.z; cs_reg[k * 4 + 3] = c4.w;
  }
  unsigned short ov[16];
  const int y = row;               // constant per thread
#pragma unroll
  for (int j = 0; j < 16; j++) {
    int x = c0 + j;
    float s = 0.f;
#pragma unroll
    for (int dil = 1; dil <= 3; dil++)
#pragma unroll
      for (int uu = 0; uu < 3; uu++)
#pragma unroll
        for (int vv = 0; vv < 3; vv++) {
          int yy = y + (uu - 1) * dil; yy = yy < 0 ? 0 : (yy > 63 ? 63 : yy);
          int xx = x + (vv - 1) * dil; xx = xx < 0 ? 0 : (xx > 63 ? 63 : xx);
          s = fmaf(wv[dil - 1][uu * 3 + vv], t[yy][xx], s);
        }
    ov[j] = bf16rne(fmaf(s, cs_reg[j], x_reg[j] * Dv));
  }
  ushort8_t o0, o1;
#pragma unroll
  for (int j = 0; j < 8; ++j) { o0[j] = ov[j]; o1[j] = ov[8 + j]; }
  *(ushort8_t*)&ypre[base + l0]     = o0;
  *(ushort8_t*)&ypre[base + l0 + 8] = o1;
}

// ---------------- bf16 transpose (B,D,L) -> (B,L,D) --------------------------
__global__ __launch_bounds__(256)
void transpose_bf16_k(const unsigned short* __restrict__ src,
                      unsigned short* __restrict__ dst)
{
  __shared__ unsigned short t[64][72];   // [l][d], pad 72
  int l0 = blockIdx.x * 64;
  int d0 = blockIdx.y * 64;
  int b  = blockIdx.z;
  int tid = threadIdx.x;
  int dl = tid & 63, lg0 = tid >> 6;
#pragma unroll
  for (int i = 0; i < 2; ++i) {
    int lg = lg0 + i * 4;                // l-chunk of 8
    ushort8_t v = *(const ushort8_t*)&src[(size_t)(b * 512 + d0 + dl) * 4096 + l0 + lg * 8];
#pragma unroll
    for (int j = 0; j < 8; ++j) t[lg * 8 + j][dl] = v[j];
  }
  __syncthreads();
  int pl = tid >> 2, c0 = (tid & 3) << 4;
  ushort8_t a = *(const ushort8_t*)&t[pl][c0];
  ushort8_t bb = *(const ushort8_t*)&t[pl][c0 + 8];
  size_t o = (size_t)(b * 4096 + l0 + pl) * 512 + d0 + c0;
  *(ushort8_t*)&dst[o] = a;
  *(ushort8_t*)&dst[o + 8] = bb;
}

// -------- LayerNorm over D + silu(z) gate, bf16 in/out ----------------------
__global__ __launch_bounds__(256)
void ln_silu_split_k(const unsigned short* __restrict__ y,
                     const unsigned short* __restrict__ z,
                     const float* __restrict__ lw, const float* __restrict__ lb,
                     unsigned short* __restrict__ hi)
{
  int wid = threadIdx.x >> 6, lane = threadIdx.x & 63;
  int pix = blockIdx.x * 4 + wid;            // 0..16383
  const unsigned short* yp = y + (size_t)pix * 512;
  const unsigned short* zp = z + (size_t)pix * 512;
  ushort8_t yv8 = *(const ushort8_t*)&yp[lane * 8];
  float vv[8];
#pragma unroll
  for (int j = 0; j < 8; j++) vv[j] = b2f(yv8[j]);
  float sum = 0.f;
#pragma unroll
  for (int j = 0; j < 8; j++) sum += vv[j];
#pragma unroll
  for (int off = 1; off < 64; off <<= 1) sum += __shfl_xor(sum, off);
  float mu = sum * (1.f / 512.f);
  float q = 0.f;
#pragma unroll
  for (int j = 0; j < 8; j++) { float dd = vv[j] - mu; q += dd * dd; }
#pragma unroll
  for (int off = 1; off < 64; off <<= 1) q += __shfl_xor(q, off);
  float rstd = rsqrtf(q * (1.f / 512.f) + 1e-5f);
  ushort8_t zv8 = *(const ushort8_t*)&zp[lane * 8];
  unsigned short oh[8];
#pragma unroll
  for (int j = 0; j < 8; j++) {
    int dch = lane * 8 + j;
    float val = (vv[j] - mu) * rstd * lw[dch] + lb[dch];
    float zv = b2f(zv8[j]);
    float ov = val * (zv * (1.f / (1.f + __expf(-zv))));
    oh[j] = bf16rne(ov);
  }
  size_t o = (size_t)pix * 512 + lane * 8;
  *(ushort4*)&hi[o]     = make_ushort4(oh[0], oh[1], oh[2], oh[3]);
  *(ushort4*)&hi[o + 4] = make_ushort4(oh[4], oh[5], oh[6], oh[7]);
}

extern "C" void kernel_launch(void* const* d_in, const int* in_sizes, int n_in,
                              void* d_out, int out_size, void* d_ws, size_t ws_size,
                              hipStream_t stream)
{
  const float* x    = (const float*)d_in[0];
  const float* win  = (const float*)d_in[1];
  const float* cw   = (const float*)d_in[2];
  const float* cb   = (const float*)d_in[3];
  const float* xpw  = (const float*)d_in[4];
  const float* dtw  = (const float*)d_in[5];
  const float* dtb  = (const float*)d_in[6];
  const float* alog = (const float*)d_in[7];
  const float* Dsv  = (const float*)d_in[8];
  const float* k1   = (const float*)d_in[9];
  const float* k2   = (const float*)d_in[10];
  const float* k3   = (const float*)d_in[11];
  const float* alp  = (const float*)d_in[12];
  const float* lw   = (const float*)d_in[13];
  const float* lb   = (const float*)d_in[14];
  const float* wout = (const float*)d_in[15];
  float* out = (float*)d_out;

  const size_t NP = (size_t)4 * 512 * 4096;   // 8,388,608 elems per (B,D,L) buffer
  float* ws = (float*)d_ws;
  float* xs     = ws;                 // Whi/Wlo -> xs fp32 -> y_t bf16 -> Ohi
  float* zbuf   = ws + NP;            // z bf16 (1st half) | ypre bf16 (2nd half)
  float* w4     = ws + 2 * NP;        // Ahi -> delta -> Yhi
  float* xdbl_r = ws + 3 * NP;        // 34 x 16384

  unsigned short* Ahi  = (unsigned short*)w4;        // 16384x512 bf16
  unsigned short* Whi  = (unsigned short*)xs;        // 1024x512 bf16
  unsigned short* Wlo  = Whi + (size_t)1024 * 512;
  unsigned short* xinb = (unsigned short*)d_out;     // xin bf16 (d_out scratch)
  unsigned short* zb16 = (unsigned short*)zbuf;              // 16384x512 bf16
  unsigned short* yp16 = zb16 + (size_t)16384 * 512;         // ypre bf16
  unsigned short* yt16 = (unsigned short*)xs;        // y_t bf16 (xs dead)
  unsigned short* Yhi  = (unsigned short*)w4;        // after delta consumed
  unsigned short* Ohi  = (unsigned short*)xs;        // after y_t consumed
  float* xsf = xs;                                   // xs fp32 view

  prep_k<<<8704, 256, 0, stream>>>(x, win, Ahi, Whi, Wlo);                  // x, win -> bf16
  gemm0_k<<<1024, 256, 0, stream>>>(Ahi, Whi, Wlo, xinb, zb16);             // xin, z (bf16)
  conv_silu_k<<<2048, 256, 0, stream>>>(xinb, cw, cb, xsf);                 // xs fp32
  xdbl_part_k<<<dim3(64, 8), 256, 0, stream>>>(xsf, xpw, out);              // partial->d_out
  xdbl_reduce_k<<<2176, 256, 0, stream>>>(out, xdbl_r);                     // xdbl_r
  delta_k<<<dim3(16, 8, 4), 256, 0, stream>>>(xdbl_r, dtw, dtb, w4);        // delta->w4
  scan_sfconv_k<<<2048, 256, 0, stream>>>(w4, xdbl_r + 32 * 16384, xsf, alog,
                                          k1, k2, k3, alp,
                                          xdbl_r + 33 * 16384, Dsv, yp16);  // ypre bf16
  transpose_bf16_k<<<dim3(64, 8, 4), 256, 0, stream>>>(yp16, yt16);         // y_t bf16
  ln_silu_split_k<<<4096, 256, 0, stream>>>(yt16, zb16, lw, lb, Yhi);       // y -> bf16
  cvt_hi_k<<<256, 256, 0, stream>>>(wout, Ohi, 65536);                      // wout -> bf16
  gemm1_k<<<512, 256, 0, stream>>>(Yhi, Ohi, out);                          // final 1-term
}

// Round 17
// 170.126 us; speedup vs baseline: 1.1601x; 1.0428x over previous
//
#include <hip/hip_runtime.h>
#include <cstddef>

// B=4, L=4096 (=64x64), d_model=512, d_inner=512, dt_rank=32, d_state=1
// GEMMs: uniform 1-term bf16 (xin already bf16-quantized on output, so the
// Wlo correction term was below that quantization noise — dropped).
// 2-phase double-buffered pipeline, BK=32, 64B-row XOR swizzle, 128x128.
// gemm0: 32 KB LDS (5 blk/CU), dual bf16 out. gemm1: 32 KB LDS, fp32 out.
// bf16 intermediates: xin, z, ypre/y_t. scan: thread-serial(16)+wave-scan.

typedef __attribute__((ext_vector_type(8))) short short8;
typedef __attribute__((ext_vector_type(8))) unsigned short ushort8_t;
typedef __attribute__((ext_vector_type(4))) float f32x4;

__device__ __forceinline__ void gload16(const void* g, void* l) {
  __builtin_amdgcn_global_load_lds(
      (const __attribute__((address_space(1))) void*)g,
      (__attribute__((address_space(3))) void*)l, 16, 0, 0);
}

__device__ __forceinline__ unsigned short bf16rne(float v) {
  unsigned u = __float_as_uint(v);
  return (unsigned short)((u + 0x7fffu + ((u >> 16) & 1u)) >> 16);
}

__device__ __forceinline__ float b2f(unsigned short u) {
  return __uint_as_float((unsigned)u << 16);
}

// ------- prep: x -> bf16 (blocks 0..8191); win -> bf16 (8192..8703) ---------
__global__ __launch_bounds__(256)
void prep_k(const float* __restrict__ x, const float* __restrict__ win,
            unsigned short* __restrict__ Ahi, unsigned short* __restrict__ Whi)
{
  int bid = blockIdx.x;
  if (bid < 8192) {
    int i = bid * 256 + threadIdx.x;            // < 2097152
    float4 v = ((const float4*)x)[i];
    ((ushort4*)Ahi)[i] = make_ushort4(bf16rne(v.x), bf16rne(v.y), bf16rne(v.z), bf16rne(v.w));
  } else {
    int i = (bid - 8192) * 256 + threadIdx.x;   // < 131072
    float4 v = ((const float4*)win)[i];
    ((ushort4*)Whi)[i] = make_ushort4(bf16rne(v.x), bf16rne(v.y), bf16rne(v.z), bf16rne(v.w));
  }
}

// ---------------- fp32 -> bf16 RNE ------------------------------------------
__global__ __launch_bounds__(256)
void cvt_hi_k(const float* __restrict__ in, unsigned short* __restrict__ hi, int n4)
{
  int i = blockIdx.x * 256 + threadIdx.x;
  if (i >= n4) return;
  float4 v = ((const float4*)in)[i];
  ((ushort4*)hi)[i] = make_ushort4(bf16rne(v.x), bf16rne(v.y), bf16rne(v.z), bf16rne(v.w));
}

// ---------------- gemm0: 128x128, BK=32, 2-phase dbuf, dual bf16 out --------
// 4 waves 2m x 2n; uniform 1-term.
__global__ __launch_bounds__(256)
void gemm0_k(const unsigned short* __restrict__ Ahi, const unsigned short* __restrict__ Whi,
             unsigned short* __restrict__ xinb, unsigned short* __restrict__ zb16)
{
  __shared__ char smem[32768];     // 2 bufs x {A 8K | B 8K}
  const int tid = threadIdx.x;
  const int wave = tid >> 6, lane = tid & 63;

  const int nwg = gridDim.x;       // 1024
  const int q = nwg >> 3, r = nwg & 7;
  const int xcd = blockIdx.x & 7, wi = blockIdx.x >> 3;
  const int logical = (xcd < r ? xcd * (q + 1) : r * (q + 1) + (xcd - r) * q) + wi;
  const int tm = logical >> 3, tn = logical & 7;
  const int m0 = tm << 7, n0 = tn << 7;

  const int wm = (wave & 1) << 6;
  const int wn = (wave >> 1) << 6;
  const int q16 = (lane >> 4) << 4;
  const int l15 = lane & 15;

  int srow[2], scol[2];
#pragma unroll
  for (int c = 0; c < 2; ++c) {
    int o = (wave << 11) + (c << 10) + (lane << 4);
    int row = o >> 6;
    srow[c] = row;
    scol[c] = (o & 63) ^ ((row & 3) << 4);
  }

  f32x4 acc[4][4];
#pragma unroll
  for (int i = 0; i < 4; ++i)
#pragma unroll
    for (int j = 0; j < 4; ++j) acc[i][j] = (f32x4){0.f, 0.f, 0.f, 0.f};

  const char* Ag = (const char*)Ahi;
  const char* Bg = (const char*)Whi;

#define G0_STAGE(buf, kt)                                                     \
  {                                                                           \
    char* base_ = smem + (buf) * 16384;                                       \
    int kb_ = (kt) << 6;                                                      \
    _Pragma("unroll")                                                         \
    for (int c = 0; c < 2; ++c) {                                             \
      int lo_ = (wave << 11) + (c << 10);                                     \
      gload16(Ag + (size_t)(m0 + srow[c]) * 1024 + kb_ + scol[c], base_ + lo_);       \
      gload16(Bg + (size_t)(n0 + srow[c]) * 1024 + kb_ + scol[c], base_ + 8192 + lo_);\
    }                                                                         \
  }

  G0_STAGE(0, 0);
  __syncthreads();
  for (int kt = 0; kt < 16; ++kt) {
    int cur = kt & 1;
    if (kt < 15) G0_STAGE(cur ^ 1, kt + 1);
    const char* bp = smem + cur * 16384;
    short8 af[4], bh[4];
#pragma unroll
    for (int i = 0; i < 4; ++i) {
      int row = wm + (i << 4) + l15;
      int cb = q16 ^ ((row & 3) << 4);
      af[i] = *(const short8*)(bp + (row << 6) + cb);
    }
#pragma unroll
    for (int j = 0; j < 4; ++j) {
      int row = wn + (j << 4) + l15;
      int cb = q16 ^ ((row & 3) << 4);
      bh[j] = *(const short8*)(bp + 8192 + (row << 6) + cb);
    }
#pragma unroll
    for (int i = 0; i < 4; ++i)
#pragma unroll
      for (int j = 0; j < 4; ++j)
        acc[i][j] = __builtin_amdgcn_mfma_f32_16x16x32_bf16(af[i], bh[j], acc[i][j], 0, 0, 0);
    __syncthreads();
  }
#undef G0_STAGE

  const int mb_base = m0 + wm + ((lane >> 4) << 2);
#pragma unroll
  for (int j = 0; j < 4; ++j) {
    int n = n0 + wn + (j << 4) + l15;
#pragma unroll
    for (int i = 0; i < 4; ++i) {
      int mb = mb_base + (i << 4);
      if (n < 512) {
        int b = mb >> 12, l = mb & 4095;
        ushort4 hv = make_ushort4(bf16rne(acc[i][j][0]), bf16rne(acc[i][j][1]),
                                  bf16rne(acc[i][j][2]), bf16rne(acc[i][j][3]));
        *(ushort4*)&xinb[((size_t)(b * 512 + n) << 12) + l] = hv;
      } else {
#pragma unroll
        for (int rr = 0; rr < 4; ++rr)
          zb16[(size_t)(mb + rr) * 512 + (n - 512)] = bf16rne(acc[i][j][rr]);
      }
    }
  }
}

// ---------------- gemm1: 128x128, BK=32, 2-phase dbuf, 1-term, fp32 out -----
__global__ __launch_bounds__(256)
void gemm1_k(const unsigned short* __restrict__ Ag_, const unsigned short* __restrict__ Whi,
             float* __restrict__ o1)
{
  __shared__ char smem[32768];     // 2 bufs x {A 8K | B 8K}
  const int tid = threadIdx.x;
  const int wave = tid >> 6, lane = tid & 63;

  const int nwg = gridDim.x;       // 512
  const int q = nwg >> 3, r = nwg & 7;
  const int xcd = blockIdx.x & 7, wi = blockIdx.x >> 3;
  const int logical = (xcd < r ? xcd * (q + 1) : r * (q + 1) + (xcd - r) * q) + wi;
  const int tm = logical >> 2, tn = logical & 3;
  const int m0 = tm << 7, n0 = tn << 7;

  const int wm = (wave & 1) << 6;
  const int wn = (wave >> 1) << 6;
  const int q16 = (lane >> 4) << 4;
  const int l15 = lane & 15;

  int srow[2], scol[2];
#pragma unroll
  for (int c = 0; c < 2; ++c) {
    int o = (wave << 11) + (c << 10) + (lane << 4);
    int row = o >> 6;
    srow[c] = row;
    scol[c] = (o & 63) ^ ((row & 3) << 4);
  }

  f32x4 acc[4][4];
#pragma unroll
  for (int i = 0; i < 4; ++i)
#pragma unroll
    for (int j = 0; j < 4; ++j) acc[i][j] = (f32x4){0.f, 0.f, 0.f, 0.f};

  const char* Ag = (const char*)Ag_;
  const char* Bg = (const char*)Whi;

#define G1_STAGE(buf, kt)                                                     \
  {                                                                           \
    char* base_ = smem + (buf) * 16384;                                       \
    int kb_ = (kt) << 6;                                                      \
    _Pragma("unroll")                                                         \
    for (int c = 0; c < 2; ++c) {                                             \
      int lo_ = (wave << 11) + (c << 10);                                     \
      gload16(Ag + (size_t)(m0 + srow[c]) * 1024 + kb_ + scol[c], base_ + lo_);       \
      gload16(Bg + (size_t)(n0 + srow[c]) * 1024 + kb_ + scol[c], base_ + 8192 + lo_);\
    }                                                                         \
  }

  G1_STAGE(0, 0);
  __syncthreads();
  for (int kt = 0; kt < 16; ++kt) {
    int cur = kt & 1;
    if (kt < 15) G1_STAGE(cur ^ 1, kt + 1);
    const char* bp = smem + cur * 16384;
    short8 af[4], bh[4];
#pragma unroll
    for (int i = 0; i < 4; ++i) {
      int row = wm + (i << 4) + l15;
      int cb = q16 ^ ((row & 3) << 4);
      af[i] = *(const short8*)(bp + (row << 6) + cb);
    }
#pragma unroll
    for (int j = 0; j < 4; ++j) {
      int row = wn + (j << 4) + l15;
      int cb = q16 ^ ((row & 3) << 4);
      bh[j] = *(const short8*)(bp + 8192 + (row << 6) + cb);
    }
#pragma unroll
    for (int i = 0; i < 4; ++i)
#pragma unroll
      for (int j = 0; j < 4; ++j)
        acc[i][j] = __builtin_amdgcn_mfma_f32_16x16x32_bf16(af[i], bh[j], acc[i][j], 0, 0, 0);
    __syncthreads();
  }
#undef G1_STAGE

  // stage C tile through LDS in two 64x128 halves; store coalesced float4
  float* sC = (float*)smem;           // 64 x 128 fp32 = 32 KB
  const int i_base = (lane >> 4) << 2;
#pragma unroll
  for (int half = 0; half < 2; ++half) {
    __syncthreads();
    if ((wave & 1) == half) {
#pragma unroll
      for (int j = 0; j < 4; ++j) {
        int nl = wn + (j << 4) + l15;
#pragma unroll
        for (int i = 0; i < 4; ++i) {
          int mloc = (i << 4) + i_base;
#pragma unroll
          for (int rr = 0; rr < 4; ++rr)
            sC[(mloc + rr) * 128 + nl] = acc[i][j][rr];
        }
      }
    }
    __syncthreads();
    int cx = (tid & 31) << 2;
    int r0 = tid >> 5;
#pragma unroll
    for (int it = 0; it < 8; ++it) {
      int row = r0 + (it << 3);
      *(float4*)&o1[(size_t)(m0 + (half << 6) + row) * 512 + n0 + cx] =
          *(float4*)&sC[row * 128 + cx];
    }
  }
}

// -------- depthwise 3x3 SAME (zero pad) + bias + silu, bf16 in, fp32 out ----
__global__ __launch_bounds__(256)
void conv_silu_k(const unsigned short* __restrict__ xin, const float* __restrict__ w,
                 const float* __restrict__ bias, float* __restrict__ xs)
{
  __shared__ float t[64][65];
  int plane = blockIdx.x;          // b*512 + d
  int d = plane & 511;
  int tid = threadIdx.x;
  const unsigned short* src = xin + (size_t)plane * 4096;
  int l0 = tid << 4, row = tid >> 2, c0 = (tid & 3) << 4;
  ushort8_t v0 = *(const ushort8_t*)&src[l0];
  ushort8_t v1 = *(const ushort8_t*)&src[l0 + 8];
#pragma unroll
  for (int j = 0; j < 8; ++j) {
    t[row][c0 + j]     = b2f(v0[j]);
    t[row][c0 + 8 + j] = b2f(v1[j]);
  }
  float wv[9];
#pragma unroll
  for (int j = 0; j < 9; j++) wv[j] = w[d * 9 + j];
  float bv = bias[d];
  __syncthreads();
  float* dst = xs + (size_t)plane * 4096;
#pragma unroll
  for (int i = 0; i < 16; i++) {
    int idx = tid + i * 256;
    int y = idx >> 6, x = idx & 63;
    float s = bv;
#pragma unroll
    for (int u = 0; u < 3; u++)
#pragma unroll
      for (int v = 0; v < 3; v++) {
        int yy = y + u - 1, xx = x + v - 1;
        if (yy >= 0 && yy < 64 && xx >= 0 && xx < 64)
          s = fmaf(wv[u * 3 + v], t[yy][xx], s);
      }
    dst[idx] = s * (1.f / (1.f + __expf(-s)));   // silu
  }
}

// ------- 3a: partial x_dbl GEMM: 8-way split over d; one pixel per thread ---
__global__ __launch_bounds__(256)
void xdbl_part_k(const float* __restrict__ xs, const float* __restrict__ xpw,
                 float* __restrict__ partial)
{
  __shared__ float sw[34 * 64];    // xpw chunk, [k][dd]
  int tid = threadIdx.x;
  int p  = blockIdx.x * 256 + tid;   // pixel 0..16383 (b*4096+l)
  int d0 = blockIdx.y * 64;
  int b = p >> 12, l = p & 4095;
  for (int i = tid; i < 34 * 64; i += 256) {
    int k = i >> 6, dd = i & 63;
    sw[i] = xpw[k * 512 + d0 + dd];
  }
  __syncthreads();
  float acc[34];
#pragma unroll
  for (int k = 0; k < 34; k++) acc[k] = 0.f;
  const float* xp = xs + (size_t)(b * 512 + d0) * 4096 + l;
#pragma unroll 4
  for (int dd = 0; dd < 64; dd++) {
    float v = xp[(size_t)dd * 4096];
#pragma unroll
    for (int k = 0; k < 34; k++) acc[k] = fmaf(sw[k * 64 + dd], v, acc[k]);
  }
  float* op = partial + (size_t)blockIdx.y * 34 * 16384 + p;
#pragma unroll
  for (int k = 0; k < 34; k++) op[(size_t)k * 16384] = acc[k];
}

// ------- 3b: reduce 8 partials -> xdbl_r[34][16384] -------------------------
__global__ __launch_bounds__(256)
void xdbl_reduce_k(const float* __restrict__ partial, float* __restrict__ xdbl_r)
{
  int gid = blockIdx.x * 256 + threadIdx.x;   // 0 .. 34*16384-1
  float s = 0.f;
#pragma unroll
  for (int sp = 0; sp < 8; sp++) s += partial[(size_t)sp * 34 * 16384 + gid];
  xdbl_r[gid] = s;
}

// ------- 3c: dts -> softplus -> delta only ----------------------------------
__global__ __launch_bounds__(256)
void delta_k(const float* __restrict__ xdbl_r, const float* __restrict__ dtw,
             const float* __restrict__ dtb, float* __restrict__ del)
{
  __shared__ float sm[32][256];    // dt-rank rows
  int tid = threadIdx.x;
  int l0 = blockIdx.x * 256;       // l tile within batch
  int d0 = blockIdx.y * 64;        // d chunk
  int b  = blockIdx.z;
  int p0 = b * 4096 + l0;
#pragma unroll
  for (int k = 0; k < 32; k++) sm[k][tid] = xdbl_r[k * 16384 + p0 + tid];
  __syncthreads();
#pragma unroll 2
  for (int dd = 0; dd < 64; dd++) {
    int d = d0 + dd;
    float s = dtb[d];
#pragma unroll
    for (int r = 0; r < 32; r++) s = fmaf(dtw[d * 32 + r], sm[r][tid], s);
    float delta = fmaxf(s, 0.f) + __logf(1.f + __expf(-fabsf(s)));  // softplus
    del[((size_t)(b * 512 + d) << 12) + l0 + tid] = delta;
  }
}

// ---- fused: a/bb on-the-fly + thread-serial(16)+wave scan + dilated convs --
__global__ __launch_bounds__(256)
void scan_sfconv_k(const float* __restrict__ del, const float* __restrict__ Bsr,
                   const float* __restrict__ xs, const float* __restrict__ A_logs,
                   const float* __restrict__ k1, const float* __restrict__ k2,
                   const float* __restrict__ k3, const float* __restrict__ alpha,
                   const float* __restrict__ Cs, const float* __restrict__ Ds,
                   unsigned short* __restrict__ ypre)
{
  __shared__ float t[64][65];      // h grid, conv source
  __shared__ float segA[4], segH[4];
  int plane = blockIdx.x;
  int d = plane & 511;
  int b = plane >> 9;
  int tid = threadIdx.x;
  int wave = tid >> 6, lane = tid & 63;
  size_t base = (size_t)plane * 4096;
  float Ad = -__expf(A_logs[d]);

  const int l0 = tid << 4;
  float a_reg[16], b_reg[16], x_reg[16];
#pragma unroll
  for (int k = 0; k < 4; ++k) {
    float4 dv4 = *(const float4*)&del[base + l0 + k * 4];
    float4 bs4 = *(const float4*)&Bsr[(b << 12) + l0 + k * 4];
    float4 xs4 = *(const float4*)&xs[base + l0 + k * 4];
    float dv[4] = {dv4.x, dv4.y, dv4.z, dv4.w};
    float bs[4] = {bs4.x, bs4.y, bs4.z, bs4.w};
    float xv[4] = {xs4.x, xs4.y, xs4.z, xs4.w};
#pragma unroll
    for (int j = 0; j < 4; ++j) {
      a_reg[k * 4 + j] = __expf(dv[j] * Ad);
      b_reg[k * 4 + j] = dv[j] * bs[j] * xv[j];
      x_reg[k * 4 + j] = xv[j];
    }
  }

  float A_th = a_reg[0], H_th = b_reg[0];
#pragma unroll
  for (int j = 1; j < 16; ++j) {
    H_th = fmaf(a_reg[j], H_th, b_reg[j]);
    A_th *= a_reg[j];
  }

#pragma unroll
  for (int off = 1; off < 64; off <<= 1) {
    float Ap = __shfl_up(A_th, off);
    float Hp = __shfl_up(H_th, off);
    if (lane >= off) { H_th = fmaf(A_th, Hp, H_th); A_th *= Ap; }
  }
  float eA = __shfl_up(A_th, 1);
  float eH = __shfl_up(H_th, 1);
  if (lane == 0) { eA = 1.f; eH = 0.f; }
  if (lane == 63) { segA[wave] = A_th; segH[wave] = H_th; }
  __syncthreads();

  float cy1 = segH[0];
  float cy2 = fmaf(segA[1], cy1, segH[1]);
  float cy3 = fmaf(segA[2], cy2, segH[2]);
  float myc = (wave == 1) ? cy1 : (wave == 2) ? cy2 : (wave == 3) ? cy3 : 0.f;
  float h = fmaf(eA, myc, eH);     // h entering this thread's segment

  int row = tid >> 2, c0 = (tid & 3) << 4;
#pragma unroll
  for (int j = 0; j < 16; ++j) {
    h = fmaf(a_reg[j], h, b_reg[j]);
    t[row][c0 + j] = h;
  }
  __syncthreads();

  float wv[3][9];
  float a0 = alpha[0], a1 = alpha[1], a2 = alpha[2];
#pragma unroll
  for (int j = 0; j < 9; j++) {
    wv[0][j] = a0 * k1[d * 9 + j];
    wv[1][j] = a1 * k2[d * 9 + j];
    wv[2][j] = a2 * k3[d * 9 + j];
  }
  float Dv = Ds[d];
  float cs_reg[16];
#pragma unroll
  for (int k = 0; k < 4; ++k) {
    float4 c4 = *(const float4*)&Cs[(b << 12) + l0 + k * 4];
    cs_reg[k * 4 + 0] = c4.x; cs_reg[k * 4 + 1] = c4.y;
    cs_reg[k * 4 + 2] = c4.z; cs_reg[k * 4 + 3] = c4.w;
  }
  unsigned short ov[16];
  const int y = row;               // constant per thread
#pragma unroll
  for (int j = 0; j < 16; j++) {
    int x = c0 + j;
    float s = 0.f;
#pragma unroll
    for (int dil = 1; dil <= 3; dil++)
#pragma unroll
      for (int uu = 0; uu < 3; uu++)
#pragma unroll
        for (int vv = 0; vv < 3; vv++) {
          int yy = y + (uu - 1) * dil; yy = yy < 0 ? 0 : (yy > 63 ? 63 : yy);
          int xx = x + (vv - 1) * dil; xx = xx < 0 ? 0 : (xx > 63 ? 63 : xx);
          s = fmaf(wv[dil - 1][uu * 3 + vv], t[yy][xx], s);
        }
    ov[j] = bf16rne(fmaf(s, cs_reg[j], x_reg[j] * Dv));
  }
  ushort8_t o0, o1;
#pragma unroll
  for (int j = 0; j < 8; ++j) { o0[j] = ov[j]; o1[j] = ov[8 + j]; }
  *(ushort8_t*)&ypre[base + l0]     = o0;
  *(ushort8_t*)&ypre[base + l0 + 8] = o1;
}

// ---------------- bf16 transpose (B,D,L) -> (B,L,D) --------------------------
__global__ __launch_bounds__(256)
void transpose_bf16_k(const unsigned short* __restrict__ src,
                      unsigned short* __restrict__ dst)
{
  __shared__ unsigned short t[64][72];   // [l][d], pad 72
  int l0 = blockIdx.x * 64;
  int d0 = blockIdx.y * 64;
  int b  = blockIdx.z;
  int tid = threadIdx.x;
  int dl = tid & 63, lg0 = tid >> 6;
#pragma unroll
  for (int i = 0; i < 2; ++i) {
    int lg = lg0 + i * 4;                // l-chunk of 8
    ushort8_t v = *(const ushort8_t*)&src[(size_t)(b * 512 + d0 + dl) * 4096 + l0 + lg * 8];
#pragma unroll
    for (int j = 0; j < 8; ++j) t[lg * 8 + j][dl] = v[j];
  }
  __syncthreads();
  int pl = tid >> 2, c0 = (tid & 3) << 4;
  ushort8_t a = *(const ushort8_t*)&t[pl][c0];
  ushort8_t bb = *(const ushort8_t*)&t[pl][c0 + 8];
  size_t o = (size_t)(b * 4096 + l0 + pl) * 512 + d0 + c0;
  *(ushort8_t*)&dst[o] = a;
  *(ushort8_t*)&dst[o + 8] = bb;
}

// -------- LayerNorm over D + silu(z) gate, bf16 in/out ----------------------
__global__ __launch_bounds__(256)
void ln_silu_split_k(const unsigned short* __restrict__ y,
                     const unsigned short* __restrict__ z,
                     const float* __restrict__ lw, const float* __restrict__ lb,
                     unsigned short* __restrict__ hi)
{
  int wid = threadIdx.x >> 6, lane = threadIdx.x & 63;
  int pix = blockIdx.x * 4 + wid;            // 0..16383
  const unsigned short* yp = y + (size_t)pix * 512;
  const unsigned short* zp = z + (size_t)pix * 512;
  ushort8_t yv8 = *(const ushort8_t*)&yp[lane * 8];
  float vv[8];
#pragma unroll
  for (int j = 0; j < 8; j++) vv[j] = b2f(yv8[j]);
  float sum = 0.f;
#pragma unroll
  for (int j = 0; j < 8; j++) sum += vv[j];
#pragma unroll
  for (int off = 1; off < 64; off <<= 1) sum += __shfl_xor(sum, off);
  float mu = sum * (1.f / 512.f);
  float q = 0.f;
#pragma unroll
  for (int j = 0; j < 8; j++) { float dd = vv[j] - mu; q += dd * dd; }
#pragma unroll
  for (int off = 1; off < 64; off <<= 1) q += __shfl_xor(q, off);
  float rstd = rsqrtf(q * (1.f / 512.f) + 1e-5f);
  ushort8_t zv8 = *(const ushort8_t*)&zp[lane * 8];
  unsigned short oh[8];
#pragma unroll
  for (int j = 0; j < 8; j++) {
    int dch = lane * 8 + j;
    float val = (vv[j] - mu) * rstd * lw[dch] + lb[dch];
    float zv = b2f(zv8[j]);
    float ov = val * (zv * (1.f / (1.f + __expf(-zv))));
    oh[j] = bf16rne(ov);
  }
  size_t o = (size_t)pix * 512 + lane * 8;
  *(ushort4*)&hi[o]     = make_ushort4(oh[0], oh[1], oh[2], oh[3]);
  *(ushort4*)&hi[o + 4] = make_ushort4(oh[4], oh[5], oh[6], oh[7]);
}

extern "C" void kernel_launch(void* const* d_in, const int* in_sizes, int n_in,
                              void* d_out, int out_size, void* d_ws, size_t ws_size,
                              hipStream_t stream)
{
  const float* x    = (const float*)d_in[0];
  const float* win  = (const float*)d_in[1];
  const float* cw   = (const float*)d_in[2];
  const float* cb   = (const float*)d_in[3];
  const float* xpw  = (const float*)d_in[4];
  const float* dtw  = (const float*)d_in[5];
  const float* dtb  = (const float*)d_in[6];
  const float* alog = (const float*)d_in[7];
  const float* Dsv  = (const float*)d_in[8];
  const float* k1   = (const float*)d_in[9];
  const float* k2   = (const float*)d_in[10];
  const float* k3   = (const float*)d_in[11];
  const float* alp  = (const float*)d_in[12];
  const float* lw   = (const float*)d_in[13];
  const float* lb   = (const float*)d_in[14];
  const float* wout = (const float*)d_in[15];
  float* out = (float*)d_out;

  const size_t NP = (size_t)4 * 512 * 4096;   // 8,388,608 elems per (B,D,L) buffer
  float* ws = (float*)d_ws;
  float* xs     = ws;                 // Whi -> xs fp32 -> y_t bf16 -> Ohi
  float* zbuf   = ws + NP;            // z bf16 (1st half) | ypre bf16 (2nd half)
  float* w4     = ws + 2 * NP;        // Ahi -> delta -> Yhi
  float* xdbl_r = ws + 3 * NP;        // 34 x 16384

  unsigned short* Ahi  = (unsigned short*)w4;        // 16384x512 bf16
  unsigned short* Whi  = (unsigned short*)xs;        // 1024x512 bf16
  unsigned short* xinb = (unsigned short*)d_out;     // xin bf16 (d_out scratch)
  unsigned short* zb16 = (unsigned short*)zbuf;              // 16384x512 bf16
  unsigned short* yp16 = zb16 + (size_t)16384 * 512;         // ypre bf16
  unsigned short* yt16 = (unsigned short*)xs;        // y_t bf16 (xs dead)
  unsigned short* Yhi  = (unsigned short*)w4;        // after delta consumed
  unsigned short* Ohi  = (unsigned short*)xs;        // after y_t consumed
  float* xsf = xs;                                   // xs fp32 view

  prep_k<<<8704, 256, 0, stream>>>(x, win, Ahi, Whi);                       // x, win -> bf16
  gemm0_k<<<1024, 256, 0, stream>>>(Ahi, Whi, xinb, zb16);                  // xin, z (bf16)
  conv_silu_k<<<2048, 256, 0, stream>>>(xinb, cw, cb, xsf);                 // xs fp32
  xdbl_part_k<<<dim3(64, 8), 256, 0, stream>>>(xsf, xpw, out);              // partial->d_out
  xdbl_reduce_k<<<2176, 256, 0, stream>>>(out, xdbl_r);                     // xdbl_r
  delta_k<<<dim3(16, 8, 4), 256, 0, stream>>>(xdbl_r, dtw, dtb, w4);        // delta->w4
  scan_sfconv_k<<<2048, 256, 0, stream>>>(w4, xdbl_r + 32 * 16384, xsf, alog,
                                          k1, k2, k3, alp,
                                          xdbl_r + 33 * 16384, Dsv, yp16);  // ypre bf16
  transpose_bf16_k<<<dim3(64, 8, 4), 256, 0, stream>>>(yp16, yt16);         // y_t bf16
  ln_silu_split_k<<<4096, 256, 0, stream>>>(yt16, zb16, lw, lb, Yhi);       // y -> bf16
  cvt_hi_k<<<256, 256, 0, stream>>>(wout, Ohi, 65536);                      // wout -> bf16
  gemm1_k<<<512, 256, 0, stream>>>(Yhi, Ohi, out);                          // final 1-term
}